// Round 9
// baseline (4014.698 us; speedup 1.0000x reference)
//
#include <hip/hip_runtime.h>
#include <hip/hip_cooperative_groups.h>
#include <math.h>

namespace cg = cooperative_groups;

// Problem constants
#define BB 512
#define SS 64
#define DD 128
#define FF 256   // 2D
#define NSYM 128
#define STK 16
#define NDEPTH 8

typedef _Float16 half_t;
typedef __attribute__((ext_vector_type(4))) _Float16 half4;
typedef __attribute__((ext_vector_type(8))) _Float16 half8;
typedef __attribute__((ext_vector_type(4))) float f32x4;

// Workspace offsets (in floats)
#define Z_OFF      0ull                    // B*S*F      = 8388608
#define QKV_OFF    8388608ull              // WT32 + GT/WvT split planes
#define QBUF_OFF   35651584ull             // B*16*768   = 6291456 (Q state)
#define PTR_OFF    41943040ull             // B*16       = 8192
#define ZF1_OFF    41951232ull             // B*256      = 131072
#define PROBS_OFF  42344448ull             // B*128      = 65536
#define DELTA_OFF  42409984ull             // B*256      = 131072 (read + quant)
#define HALT_OFF   42541056ull             // B          = 512
#define WACT_OFF   42542080ull             // B          = 512
#define MAGP_OFF   42542592ull             // B*2        = 1024
#define MQKV_OFF   42740224ull             // MT32 fp32 [768][256] = 196608
#define CB2_OFF    42936832ull             // 128

// ---------------------------------------------------------------------------
// Combined transposed weight, fp32: WT32[col=h*256+c][e] = W_h[e][c]
__global__ void k_buildwt32(const float* __restrict__ wr, const float* __restrict__ wi,
                            float* __restrict__ WT32) {
    int idx = blockIdx.x * 256 + threadIdx.x;   // 196608 total, grid=768
    if (idx >= 768 * 256) return;
    int col = idx >> 8;
    int e   = idx & 255;
    int h   = col >> 8;
    int c   = col & 255;
    const float* Wr = wr + h * DD * DD;
    const float* Wi = wi + h * DD * DD;
    float v;
    if (c < DD) {
        v = (e < DD) ? Wr[c * DD + e] : -Wi[c * DD + (e - DD)];
    } else {
        int j = c - DD;
        v = (e < DD) ? Wi[j * DD + e] : Wr[j * DD + (e - DD)];
    }
    WT32[idx] = v;
}

// GT[n][e] = G[e][n] = sum_c Wq[e][c]*Wk[n][c], split to fp16 h/l (unscaled).
__global__ __launch_bounds__(256) void k_buildG(const float* __restrict__ WT32,
                                                half_t* __restrict__ GTh,
                                                half_t* __restrict__ GTl) {
    __shared__ float kcol[256];
    int n = blockIdx.x;
    int e = threadIdx.x;
    kcol[e] = WT32[65536 + e * 256 + n];   // Wk[n][c=e]
    __syncthreads();
    float s = 0.f;
    for (int c = 0; c < 256; ++c) s += kcol[c] * WT32[c * 256 + e];  // Wq[e][c]
    half_t h = (half_t)s;
    GTh[n * 256 + e] = h;
    GTl[n * 256 + e] = (half_t)(s - (float)h);
}

__global__ void k_splitWv(const float* __restrict__ WT32,
                          half_t* __restrict__ WvTh, half_t* __restrict__ WvTl) {
    int idx = blockIdx.x * 256 + threadIdx.x;   // 65536, grid 256
    float v = WT32[131072 + idx];   // WvT[n][e]
    half_t h = (half_t)v;
    WvTh[idx] = h;
    WvTl[idx] = (half_t)(v - (float)h);
}

__global__ void k_cb2(const float* __restrict__ cb, float* __restrict__ cb2) {
    int n = threadIdx.x;   // 128 threads
    float s = 0.f;
    for (int c = 0; c < FF; ++c) { float v = cb[n * FF + c]; s += v * v; }
    cb2[n] = s;
}

// ---------------------------------------------------------------------------
// Attention step for one batch (R6 k_attn8 body), as a device function.
// 512 threads; smem layout (bytes): Zh@0(33792) Zl@33792 U0@67584(36864)
// U1@104448 P0@141312(9216) P1@150528  -> 159744 total.
__device__ __forceinline__ void attn_step(
        int b, int tid, char* smem,
        const half_t* __restrict__ GTh, const half_t* __restrict__ GTl,
        const half_t* __restrict__ WvTh, const half_t* __restrict__ WvTl,
        const float* __restrict__ delta, const float* __restrict__ wact,
        float* __restrict__ z, float* __restrict__ acc, float* __restrict__ zf1g) {
    half_t* Zh = (half_t*)smem;
    half_t* Zl = (half_t*)(smem + 33792);
    half_t* U0 = (half_t*)(smem + 67584);
    half_t* U1 = (half_t*)(smem + 104448);
    half_t* P0 = (half_t*)(smem + 141312);
    half_t* P1 = (half_t*)(smem + 150528);

    int w = tid >> 6, lane = tid & 63;
    int l15 = lane & 15, lq = lane >> 4;
    float* zb = z + (size_t)b * (SS * FF);
    float* accb = acc + (size_t)b * (SS * FF);

    // ---- phase 0: x0 = z + 0.1*delta; deferred acc; split to LDS
    float wa = wact[b];
    f32x4 dv = *(const f32x4*)(delta + b * FF + lane * 4);
    bool doacc = (wa != 0.0f);
#pragma unroll
    for (int it = 0; it < 8; ++it) {
        int i = w * 8 + it;
        f32x4 zv = *(const f32x4*)(zb + (size_t)i * FF + lane * 4);
        f32x4 x0;
#pragma unroll
        for (int jj = 0; jj < 4; ++jj) x0[jj] = zv[jj] + 0.1f * dv[jj];
        if (doacc) {
            f32x4 av = *(const f32x4*)(accb + (size_t)i * FF + lane * 4);
#pragma unroll
            for (int jj = 0; jj < 4; ++jj) av[jj] += wa * x0[jj];
            *(f32x4*)(accb + (size_t)i * FF + lane * 4) = av;
        }
        half4 h4, l4;
#pragma unroll
        for (int jj = 0; jj < 4; ++jj) {
            half_t h = (half_t)x0[jj];
            h4[jj] = h; l4[jj] = (half_t)(x0[jj] - (float)h);
        }
        *(half4*)&Zh[i * 264 + lane * 4] = h4;
        *(half4*)&Zl[i * 264 + lane * 4] = l4;
    }
    __syncthreads();   // Z staged

    // ---- phase T: T = x0 @ G, wave w owns 32-col band.
    {
        f32x4 tac[4][2];
#pragma unroll
        for (int mt = 0; mt < 4; ++mt)
#pragma unroll
            for (int nt = 0; nt < 2; ++nt) tac[mt][nt] = (f32x4){0.f, 0.f, 0.f, 0.f};
        for (int kt = 0; kt < 8; ++kt) {
            int kc = kt * 32 + lq * 8;
            half8 ah[4], al[4], gh[2], gl[2];
#pragma unroll
            for (int mt = 0; mt < 4; ++mt) {
                int ro = (mt * 16 + l15) * 264 + kc;
                ah[mt] = *(const half8*)&Zh[ro];
                al[mt] = *(const half8*)&Zl[ro];
            }
#pragma unroll
            for (int nt = 0; nt < 2; ++nt) {
                size_t go = (size_t)(w * 32 + nt * 16 + l15) * 256 + kc;
                gh[nt] = *(const half8*)(GTh + go);
                gl[nt] = *(const half8*)(GTl + go);
            }
#pragma unroll
            for (int mt = 0; mt < 4; ++mt)
#pragma unroll
                for (int nt = 0; nt < 2; ++nt) {
                    tac[mt][nt] = __builtin_amdgcn_mfma_f32_16x16x32_f16(ah[mt], gh[nt], tac[mt][nt], 0, 0, 0);
                    tac[mt][nt] = __builtin_amdgcn_mfma_f32_16x16x32_f16(ah[mt], gl[nt], tac[mt][nt], 0, 0, 0);
                    tac[mt][nt] = __builtin_amdgcn_mfma_f32_16x16x32_f16(al[mt], gh[nt], tac[mt][nt], 0, 0, 0);
                }
        }
        const float scale = 0.08838834764831845f;
#pragma unroll
        for (int mt = 0; mt < 4; ++mt)
#pragma unroll
            for (int nt = 0; nt < 2; ++nt)
#pragma unroll
                for (int r = 0; r < 4; ++r) {
                    int m = mt * 16 + lq * 4 + r;
                    int n = w * 32 + nt * 16 + l15;
                    float v = tac[mt][nt][r] * scale;
                    half_t h = (half_t)v;
                    U0[m * 264 + n] = h;
                    U1[m * 264 + n] = (half_t)(v - (float)h);
                }
    }
    __syncthreads();   // T ready

    // ---- phase B: waves 0-3: S/softmax/P; all waves: V band.
    if (w < 4) {
        f32x4 sac[4];
#pragma unroll
        for (int jt = 0; jt < 4; ++jt) sac[jt] = (f32x4){0.f, 0.f, 0.f, 0.f};
        for (int kt = 0; kt < 8; ++kt) {
            int kc = kt * 32 + lq * 8;
            int to = (w * 16 + l15) * 264 + kc;
            half8 bh = *(const half8*)&U0[to];
            half8 bl = *(const half8*)&U1[to];
            half8 ah[4], al[4];
#pragma unroll
            for (int jt = 0; jt < 4; ++jt) {
                int ro = (jt * 16 + l15) * 264 + kc;
                ah[jt] = *(const half8*)&Zh[ro];
                al[jt] = *(const half8*)&Zl[ro];
            }
#pragma unroll
            for (int jt = 0; jt < 4; ++jt) {
                sac[jt] = __builtin_amdgcn_mfma_f32_16x16x32_f16(ah[jt], bh, sac[jt], 0, 0, 0);
                sac[jt] = __builtin_amdgcn_mfma_f32_16x16x32_f16(ah[jt], bl, sac[jt], 0, 0, 0);
                sac[jt] = __builtin_amdgcn_mfma_f32_16x16x32_f16(al[jt], bh, sac[jt], 0, 0, 0);
            }
        }
        float sv[4][4];
        float mx = -1e30f;
#pragma unroll
        for (int jt = 0; jt < 4; ++jt)
#pragma unroll
            for (int r = 0; r < 4; ++r) { sv[jt][r] = sac[jt][r]; mx = fmaxf(mx, sv[jt][r]); }
        mx = fmaxf(mx, __shfl_xor(mx, 16));
        mx = fmaxf(mx, __shfl_xor(mx, 32));
        float ssum = 0.f;
#pragma unroll
        for (int jt = 0; jt < 4; ++jt)
#pragma unroll
            for (int r = 0; r < 4; ++r) { float e = expf(sv[jt][r] - mx); sv[jt][r] = e; ssum += e; }
        ssum += __shfl_xor(ssum, 16);
        ssum += __shfl_xor(ssum, 32);
        float inv = 1.f / ssum;
#pragma unroll
        for (int jt = 0; jt < 4; ++jt) {
            half4 h4, l4;
#pragma unroll
            for (int r = 0; r < 4; ++r) {
                float pv = sv[jt][r] * inv;
                half_t hh = (half_t)pv;
                h4[r] = hh;
                l4[r] = (half_t)(pv - (float)hh);
            }
            *(half4*)&P0[w * 1152 + l15 * 72 + jt * 16 + lq * 4] = h4;
            *(half4*)&P1[w * 1152 + l15 * 72 + jt * 16 + lq * 4] = l4;
        }
    }

    f32x4 vac[4][2];
#pragma unroll
    for (int mt = 0; mt < 4; ++mt)
#pragma unroll
        for (int nt = 0; nt < 2; ++nt) vac[mt][nt] = (f32x4){0.f, 0.f, 0.f, 0.f};
    for (int kt = 0; kt < 8; ++kt) {
        int kc = kt * 32 + lq * 8;
        half8 ah[4], al[4], gh[2], gl[2];
#pragma unroll
        for (int mt = 0; mt < 4; ++mt) {
            int ro = (mt * 16 + l15) * 264 + kc;
            ah[mt] = *(const half8*)&Zh[ro];
            al[mt] = *(const half8*)&Zl[ro];
        }
#pragma unroll
        for (int nt = 0; nt < 2; ++nt) {
            size_t go = (size_t)(w * 32 + nt * 16 + l15) * 256 + kc;
            gh[nt] = *(const half8*)(WvTh + go);
            gl[nt] = *(const half8*)(WvTl + go);
        }
#pragma unroll
        for (int mt = 0; mt < 4; ++mt)
#pragma unroll
            for (int nt = 0; nt < 2; ++nt) {
                vac[mt][nt] = __builtin_amdgcn_mfma_f32_16x16x32_f16(ah[mt], gh[nt], vac[mt][nt], 0, 0, 0);
                vac[mt][nt] = __builtin_amdgcn_mfma_f32_16x16x32_f16(ah[mt], gl[nt], vac[mt][nt], 0, 0, 0);
                vac[mt][nt] = __builtin_amdgcn_mfma_f32_16x16x32_f16(al[mt], gh[nt], vac[mt][nt], 0, 0, 0);
            }
    }
    __syncthreads();   // S done reading T

    // VT write
#pragma unroll
    for (int mt = 0; mt < 4; ++mt)
#pragma unroll
        for (int nt = 0; nt < 2; ++nt) {
            int n = w * 32 + nt * 16 + l15;
            int m0 = mt * 16 + lq * 4;
            half4 h4, l4;
#pragma unroll
            for (int r = 0; r < 4; ++r) {
                float v = vac[mt][nt][r];
                half_t h = (half_t)v;
                h4[r] = h; l4[r] = (half_t)(v - (float)h);
            }
            *(half4*)&U0[n * 72 + m0] = h4;
            *(half4*)&U1[n * 72 + m0] = l4;
        }
    __syncthreads();   // VT + P visible

    // ---- phase O
    f32x4 oc[4][2];
#pragma unroll
    for (int mt = 0; mt < 4; ++mt)
#pragma unroll
        for (int nt = 0; nt < 2; ++nt) oc[mt][nt] = (f32x4){0.f, 0.f, 0.f, 0.f};
#pragma unroll
    for (int kt = 0; kt < 2; ++kt) {
        half8 pah[4], pal[4];
#pragma unroll
        for (int mt = 0; mt < 4; ++mt) {
            int po = l15 * 72 + kt * 32 + lq * 8;
            pah[mt] = *(const half8*)&P0[mt * 1152 + po];
            pal[mt] = *(const half8*)&P1[mt * 1152 + po];
        }
#pragma unroll
        for (int nt = 0; nt < 2; ++nt) {
            int n = w * 32 + nt * 16 + l15;
            half8 vbh = *(const half8*)&U0[n * 72 + kt * 32 + lq * 8];
            half8 vbl = *(const half8*)&U1[n * 72 + kt * 32 + lq * 8];
#pragma unroll
            for (int mt = 0; mt < 4; ++mt) {
                oc[mt][nt] = __builtin_amdgcn_mfma_f32_16x16x32_f16(pah[mt], vbh, oc[mt][nt], 0, 0, 0);
                oc[mt][nt] = __builtin_amdgcn_mfma_f32_16x16x32_f16(pah[mt], vbl, oc[mt][nt], 0, 0, 0);
                oc[mt][nt] = __builtin_amdgcn_mfma_f32_16x16x32_f16(pal[mt], vbh, oc[mt][nt], 0, 0, 0);
            }
        }
    }

    // ---- epilogue: z_out = O + 0.1*x0; zf1 col-means for this wave's band
    float zfs[2] = {0.f, 0.f};
#pragma unroll
    for (int mt = 0; mt < 4; ++mt)
#pragma unroll
        for (int nt = 0; nt < 2; ++nt)
#pragma unroll
            for (int r = 0; r < 4; ++r) {
                int i = mt * 16 + lq * 4 + r;
                int c = w * 32 + nt * 16 + l15;
                int zo = i * 264 + c;
                float x0 = (float)Zh[zo] + (float)Zl[zo];
                float z1 = oc[mt][nt][r] + 0.1f * x0;
                zb[(size_t)i * FF + c] = z1;
                zfs[nt] += z1;
            }
#pragma unroll
    for (int nt = 0; nt < 2; ++nt) {
        zfs[nt] += __shfl_xor(zfs[nt], 16);
        zfs[nt] += __shfl_xor(zfs[nt], 32);
    }
    if (lq == 0) {
#pragma unroll
        for (int nt = 0; nt < 2; ++nt)
            zf1g[b * FF + w * 32 + nt * 16 + l15] = zfs[nt] * (1.f / 64.f);
    }
}

// ---------------------------------------------------------------------------
// Stack step for one batch: gate -> ptr -> zfW (fp32 dot) -> Q recurrence ->
// memattn -> read/zf2/pval (LDS slots) -> mag partials (global).
// smem float layout: zfS@0(256) red@256(512) Qs@768(16*776) sm@13184(272)
// rowmax@13456 rowsum@13472 pw@13488 oldp@13504 np@13520 g@13536 zw@13552(768)
// zf2s@14336(2*256) reads@14848(2*256) pvals@15360(2)
__device__ __forceinline__ void stack_step(
        int b, int slot, int tid, char* smem,
        const float* __restrict__ MT32,
        const float* __restrict__ ctrl_w, const float* __restrict__ ctrl_b,
        const float* __restrict__ halt_w, const float* __restrict__ halt_b,
        float* __restrict__ ptrv, float* __restrict__ qbuf,
        const float* __restrict__ z, const float* __restrict__ zf1g,
        float* __restrict__ magpart) {
    float* F = (float*)smem;
    float* zfS = F;
    float* red = F + 256;
    float* Qs  = F + 768;
    float* sms = F + 13184;
    float* rowmax = F + 13456;
    float* rowsum = F + 13472;
    float* pw  = F + 13488;
    float* oldp= F + 13504;
    float* np  = F + 13520;
    float* gg  = F + 13536;
    float* zw  = F + 13552;
    float* zf2s = F + 14336;
    float* reads= F + 14848;
    float* pvals= F + 15360;

    int w = tid >> 6, lane = tid & 63;

    if (tid < 256) zfS[tid] = zf1g[b * FF + tid];
    if (tid < 16) oldp[tid] = ptrv[b * STK + tid];
    __syncthreads();

    if (w < 3) {
        float s = 0.f;
#pragma unroll
        for (int q = 0; q < 4; ++q) {
            int c = lane + 64 * q;
            s += zfS[c] * ctrl_w[c * 3 + w];
        }
#pragma unroll
        for (int off = 1; off < 64; off <<= 1) s += __shfl_xor(s, off);
        if (lane == 0) gg[w] = 1.f / (1.f + expf(-(s + ctrl_b[w])));
    }
    __syncthreads();
    float tot = gg[0] + gg[1] + gg[2] + 1e-6f;
    float push = gg[0] / tot, pop = gg[1] / tot, stay = gg[2] / tot;
    if (tid < 16) {
        float v = push * oldp[(tid + 15) & 15] + pop * oldp[(tid + 1) & 15] + stay * oldp[tid];
        np[tid] = v;
        ptrv[b * STK + tid] = v;
    }

    // zfW = zf1 @ W  (exact fp32 dot against MT32[col][e])
    {
        float s = 0.f;
        const float* mrow = MT32 + (size_t)tid * 256;
        for (int e = 0; e < 256; e += 4) {
            f32x4 m4 = *(const f32x4*)(mrow + e);
            s += m4[0] * zfS[e] + m4[1] * zfS[e + 1] + m4[2] * zfS[e + 2] + m4[3] * zfS[e + 3];
        }
        zw[tid] = s;
        if (tid < 256) {
            float s2 = 0.f;
            const float* mrow2 = MT32 + (size_t)(512 + tid) * 256;
            for (int e = 0; e < 256; e += 4) {
                f32x4 m4 = *(const f32x4*)(mrow2 + e);
                s2 += m4[0] * zfS[e] + m4[1] * zfS[e + 1] + m4[2] * zfS[e + 2] + m4[3] * zfS[e + 3];
            }
            zw[512 + tid] = s2;
        }
    }
    __syncthreads();

    // Q recurrence: Q = (1-push)*Q + push*zfW (bcast over 16 slots)
    float omp = 1.f - push;
    float* qb = qbuf + (size_t)b * (STK * 768);
#pragma unroll 4
    for (int t16 = 0; t16 < 16; ++t16) {
        {
            float q = qb[t16 * 768 + tid] * omp + push * zw[tid];
            qb[t16 * 768 + tid] = q;
            Qs[t16 * 776 + tid] = q;
        }
        if (tid < 256) {
            int c = 512 + tid;
            float q = qb[t16 * 768 + c] * omp + push * zw[c];
            qb[t16 * 768 + c] = q;
            Qs[t16 * 776 + c] = q;
        }
    }
    __syncthreads();

    // memattn
    if (tid < 256) {
        int i = tid >> 4, j = tid & 15;
        float s = 0.f;
#pragma unroll 4
        for (int c = 0; c < 256; c += 4) {
            f32x4 qi = *(const f32x4*)&Qs[i * 776 + c];
            f32x4 kj = *(const f32x4*)&Qs[j * 776 + 256 + c];
            s += qi[0] * kj[0] + qi[1] * kj[1] + qi[2] * kj[2] + qi[3] * kj[3];
        }
        sms[i * 17 + j] = s * 0.08838834764831845f;
    }
    __syncthreads();
    if (tid < 16) {
        float m = -1e30f;
        for (int jj = 0; jj < 16; ++jj) m = fmaxf(m, sms[tid * 17 + jj]);
        float su = 0.f;
        for (int jj = 0; jj < 16; ++jj) su += expf(sms[tid * 17 + jj] - m);
        rowmax[tid] = m; rowsum[tid] = su;
    }
    __syncthreads();
    if (tid < 256) {
        int i = tid >> 4, j = tid & 15;
        sms[i * 17 + j] = expf(sms[i * 17 + j] - rowmax[i]) / rowsum[i];
    }
    __syncthreads();
    if (tid < 16) {
        float a = 0.f;
        for (int s2 = 0; s2 < 16; ++s2) a += np[s2] * sms[s2 * 17 + tid];
        pw[tid] = a;
    }
    __syncthreads();
    if (tid < 256) {
        float a = 0.f;
#pragma unroll
        for (int jj = 0; jj < 16; ++jj) a += pw[jj] * Qs[jj * 776 + 512 + tid];
        reads[slot * 256 + tid] = a;
        zf2s[slot * 256 + tid] = zfS[tid] + 0.1f * a;
    }
    __syncthreads();

    // pval
    {
        float hp = (tid < 256) ? zf2s[slot * 256 + tid] * halt_w[tid] : 0.f;
        red[tid] = hp;
        __syncthreads();
        for (int off = 256; off > 0; off >>= 1) {
            if (tid < off) red[tid] += red[tid + off];
            __syncthreads();
        }
        if (tid == 0) pvals[slot] = 1.f / (1.f + expf(-(red[0] + halt_b[0])));
        __syncthreads();
    }

    // mag sweep over this batch's z (+0.1*read)
    {
        int d = tid & 127, seg = tid >> 7;
        float rr = 0.1f * reads[slot * 256 + d];
        float ri = 0.1f * reads[slot * 256 + DD + d];
        const float* zb = z + (size_t)b * (SS * FF);
        float ms = 0.f, msq = 0.f;
#pragma unroll 4
        for (int r16 = 0; r16 < 16; ++r16) {
            int srow = seg * 16 + r16;
            float zr = zb[srow * FF + d] + rr;
            float zi = zb[srow * FF + DD + d] + ri;
            float m2 = zr * zr + zi * zi;
            ms += sqrtf(m2); msq += m2;
        }
        red[tid] = ms;
        __syncthreads();
        for (int off = 256; off > 0; off >>= 1) {
            if (tid < off) red[tid] += red[tid + off];
            __syncthreads();
        }
        float tms = red[0];
        __syncthreads();
        red[tid] = msq;
        __syncthreads();
        for (int off = 256; off > 0; off >>= 1) {
            if (tid < off) red[tid] += red[tid + off];
            __syncthreads();
        }
        if (tid == 0) { magpart[2 * b] = tms; magpart[2 * b + 1] = red[0]; }
        __syncthreads();
    }
}

// ---------------------------------------------------------------------------
// VQ + ACT for one batch. Uses slots written by stack_step (LDS persists).
// vq scratch: red2@16384(512) pr@16896(128) dsum@17024(512) gsum@17536(512)
__device__ __forceinline__ void vq_step(
        int b, int slot, int t, int tid, char* smem,
        const float* __restrict__ cb, const float* __restrict__ cb2,
        const float* __restrict__ adj,
        float* __restrict__ probs, float* __restrict__ delta,
        float* __restrict__ halt, float* __restrict__ wact,
        const float* __restrict__ magpart) {
    float* F = (float*)smem;
    float* zf2s = F + 14336;
    float* reads = F + 14848;
    float* pvals = F + 15360;
    float* red = F + 16384;
    float* pr  = F + 16896;
    float* dsum= F + 17024;
    float* gsum= F + 17536;

    const float* zf = zf2s + slot * 256;

    float up = 0.f;
    if (t > 0) {
        red[tid] = magpart[2 * tid];
        __syncthreads();
        for (int off = 256; off > 0; off >>= 1) {
            if (tid < off) red[tid] += red[tid + off];
            __syncthreads();
        }
        float tms = red[0];
        __syncthreads();
        red[tid] = magpart[2 * tid + 1];
        __syncthreads();
        for (int off = 256; off > 0; off >>= 1) {
            if (tid < off) red[tid] += red[tid + off];
            __syncthreads();
        }
        float tmsq = red[0];
        __syncthreads();
        const float N = 4194304.f;   // B*S*D
        float mean = tms / N;
        float var = tmsq / N - mean * mean;
        float x = var / (1.f + 1e-6f);
        up = (x > 20.f) ? x : log1pf(expf(x));
    }

    // zz = ||zf2||^2
    red[tid] = (tid < 256) ? zf[tid] * zf[tid] : 0.f;
    __syncthreads();
    for (int off = 256; off > 0; off >>= 1) {
        if (tid < off) red[tid] += red[tid + off];
        __syncthreads();
    }
    float zz = red[0];
    __syncthreads();

    // dist + gb partials: n = tid>>2, part = tid&3
    {
        int n = tid >> 2, part = tid & 3;
        float dacc = 0.f;
        const float* cbn = cb + n * FF + part * 64;
        const float* zfp = zf + part * 64;
        for (int c2 = 0; c2 < 64; c2 += 4) {
            f32x4 cv = *(const f32x4*)(cbn + c2);
            dacc += cv[0] * zfp[c2] + cv[1] * zfp[c2 + 1] + cv[2] * zfp[c2 + 2] + cv[3] * zfp[c2 + 3];
        }
        dsum[tid] = dacc;
        float gacc = 0.f;
        if (t > 0) {
            const float* pp = probs + b * NSYM + part * 32;
            for (int k = 0; k < 32; ++k) gacc += pp[k] * adj[(part * 32 + k) * NSYM + n];
        }
        gsum[tid] = gacc;
    }
    __syncthreads();

    float vval = -1e30f;
    if (tid < 128) {
        int n = tid;
        float dot = dsum[n * 4] + dsum[n * 4 + 1] + dsum[n * 4 + 2] + dsum[n * 4 + 3];
        float dist = (zz + cb2[n] - 2.f * dot) * (1.f / 256.f);
        float dtot = dist;
        if (t > 0) {
            float gb = gsum[n * 4] + gsum[n * 4 + 1] + gsum[n * 4 + 2] + gsum[n * 4 + 3];
            dtot = dist - 0.01f * up * (1.f / (1.f + expf(-gb)));
        }
        vval = -dtot;
        red[tid] = vval;
    }
    __syncthreads();
    for (int off = 64; off > 0; off >>= 1) {
        if (tid < off) red[tid] = fmaxf(red[tid], red[tid + off]);
        __syncthreads();
    }
    float mx = red[0];
    __syncthreads();
    float e = 0.f;
    if (tid < 128) { e = expf(vval - mx); red[tid] = e; }
    __syncthreads();
    for (int off = 64; off > 0; off >>= 1) {
        if (tid < off) red[tid] += red[tid + off];
        __syncthreads();
    }
    float se = red[0];
    __syncthreads();
    if (tid < 128) {
        float psm = e / se;
        pr[tid] = psm;
        probs[b * NSYM + tid] = psm;
    }
    __syncthreads();

    // quant + delta = read + quant
    {
        int c = tid & 255, part = tid >> 8;
        float q = 0.f;
        const float* cbc = cb + part * 64 * FF + c;
        for (int k = 0; k < 64; ++k) q += pr[part * 64 + k] * cbc[k * FF];
        red[tid] = q;
    }
    __syncthreads();
    if (tid < 256) {
        float q = red[tid] + red[256 + tid];
        delta[b * FF + tid] = reads[slot * 256 + tid] + q;
    }
    if (tid == 0) {
        float h = halt[b], p = pvals[slot];
        float running = (h < 0.99f) ? 1.f : 0.f;
        float w2 = (((h + p * running) >= 0.99f) ? (1.f - h) : p) * running;
        halt[b] = h + w2;
        wact[b] = w2;
    }
    __syncthreads();
}

// ---------------------------------------------------------------------------
// Persistent cooperative mega-kernel: 256 blocks x 512 thr, 2 batches/block.
__global__ __launch_bounds__(512, 1) void k_uber(
        const float* __restrict__ z_real, const float* __restrict__ z_imag,
        const half_t* __restrict__ GTh, const half_t* __restrict__ GTl,
        const half_t* __restrict__ WvTh, const half_t* __restrict__ WvTl,
        const float* __restrict__ MT32,
        const float* __restrict__ ctrl_w, const float* __restrict__ ctrl_b,
        const float* __restrict__ halt_w, const float* __restrict__ halt_b,
        const float* __restrict__ cb, const float* __restrict__ cb2,
        const float* __restrict__ adj,
        float* __restrict__ z, float* __restrict__ qbuf, float* __restrict__ ptrv,
        float* __restrict__ probs, float* __restrict__ halt,
        float* __restrict__ delta, float* __restrict__ wact,
        float* __restrict__ magpart, float* __restrict__ zf1g,
        float* __restrict__ acc) {
    __shared__ __align__(16) char smem[159744];
    int tid = threadIdx.x;
    int b0 = blockIdx.x, b1 = blockIdx.x + 256;

    // ---- init (all per-batch state owned by this block) ----
#pragma unroll
    for (int s = 0; s < 2; ++s) {
        int b = (s == 0) ? b0 : b1;
        for (int i = tid; i < SS * FF; i += 512) {
            int c = i & 255;
            int row = i >> 8;
            size_t gi = (size_t)b * (SS * FF) + i;
            z[gi] = (c < DD) ? z_real[((size_t)b * SS + row) * DD + c]
                             : z_imag[((size_t)b * SS + row) * DD + (c - DD)];
            acc[gi] = 0.f;
        }
        for (int i = tid; i < STK * 768; i += 512) qbuf[(size_t)b * (STK * 768) + i] = 0.f;
        if (tid < FF) delta[b * FF + tid] = 0.f;
        if (tid < STK) ptrv[b * STK + tid] = (tid == 0) ? 1.f : 0.f;
        if (tid < NSYM) probs[b * NSYM + tid] = 0.f;
        if (tid == 0) { halt[b] = 0.f; wact[b] = 0.f; }
    }
    __syncthreads();

    cg::grid_group grid = cg::this_grid();

    for (int t = 0; t < NDEPTH; ++t) {
        attn_step(b0, tid, smem, GTh, GTl, WvTh, WvTl, delta, wact, z, acc, zf1g);
        __syncthreads();
        attn_step(b1, tid, smem, GTh, GTl, WvTh, WvTl, delta, wact, z, acc, zf1g);
        __syncthreads();
        stack_step(b0, 0, tid, smem, MT32, ctrl_w, ctrl_b, halt_w, halt_b,
                   ptrv, qbuf, z, zf1g, magpart);
        __syncthreads();
        stack_step(b1, 1, tid, smem, MT32, ctrl_w, ctrl_b, halt_w, halt_b,
                   ptrv, qbuf, z, zf1g, magpart);
        grid.sync();    // magpart from ALL batches visible
        vq_step(b0, 0, t, tid, smem, cb, cb2, adj, probs, delta, halt, wact, magpart);
        __syncthreads();
        vq_step(b1, 1, t, tid, smem, cb, cb2, adj, probs, delta, halt, wact, magpart);
        grid.sync();    // protect magpart reads from next step's writes
    }

    // ---- final deferred delta/acc ----
#pragma unroll
    for (int s = 0; s < 2; ++s) {
        int b = (s == 0) ? b0 : b1;
        float wa = wact[b];
        if (wa != 0.0f) {
            for (int i = tid; i < SS * FF; i += 512) {
                int c = i & 255;
                size_t gi = (size_t)b * (SS * FF) + i;
                acc[gi] += wa * (z[gi] + 0.1f * delta[b * FF + c]);
            }
        }
    }
}

// ---------------------------------------------------------------------------
extern "C" void kernel_launch(void* const* d_in, const int* in_sizes, int n_in,
                              void* d_out, int out_size, void* d_ws, size_t ws_size,
                              hipStream_t stream) {
    const float* z_real  = (const float*)d_in[0];
    const float* z_imag  = (const float*)d_in[1];
    const float* attn_wr = (const float*)d_in[2];
    const float* attn_wi = (const float*)d_in[3];
    const float* mem_wr  = (const float*)d_in[4];
    const float* mem_wi  = (const float*)d_in[5];
    const float* ctrl_w  = (const float*)d_in[6];
    const float* ctrl_b  = (const float*)d_in[7];
    const float* halt_w  = (const float*)d_in[8];
    const float* halt_b  = (const float*)d_in[9];
    const float* codebook  = (const float*)d_in[10];
    const float* adjacency = (const float*)d_in[11];

    float* ws = (float*)d_ws;
    float* z      = ws + Z_OFF;
    float* WT32   = ws + QKV_OFF;
    half_t* GTh   = (half_t*)(ws + QKV_OFF + 196608);
    half_t* GTl   = GTh + 65536;
    half_t* WvTh  = GTl + 65536;
    half_t* WvTl  = WvTh + 65536;
    float* qbuf   = ws + QBUF_OFF;
    float* ptrv   = ws + PTR_OFF;
    float* zf1    = ws + ZF1_OFF;
    float* probs  = ws + PROBS_OFF;
    float* delta  = ws + DELTA_OFF;
    float* halt   = ws + HALT_OFF;
    float* wact   = ws + WACT_OFF;
    float* magp   = ws + MAGP_OFF;
    float* MT32   = ws + MQKV_OFF;
    float* cb2    = ws + CB2_OFF;
    float* acc    = (float*)d_out;

    k_buildwt32<<<768, 256, 0, stream>>>(attn_wr, attn_wi, WT32);
    k_buildG<<<256, 256, 0, stream>>>(WT32, GTh, GTl);
    k_splitWv<<<256, 256, 0, stream>>>(WT32, WvTh, WvTl);
    k_buildwt32<<<768, 256, 0, stream>>>(mem_wr, mem_wi, MT32);
    k_cb2<<<1, 128, 0, stream>>>(codebook, cb2);

    void* args[] = {
        (void*)&z_real, (void*)&z_imag,
        (void*)&GTh, (void*)&GTl, (void*)&WvTh, (void*)&WvTl,
        (void*)&MT32,
        (void*)&ctrl_w, (void*)&ctrl_b, (void*)&halt_w, (void*)&halt_b,
        (void*)&codebook, (void*)&cb2, (void*)&adjacency,
        (void*)&z, (void*)&qbuf, (void*)&ptrv, (void*)&probs, (void*)&halt,
        (void*)&delta, (void*)&wact, (void*)&magp, (void*)&zf1, (void*)&acc
    };
    hipLaunchCooperativeKernel((const void*)k_uber, dim3(256), dim3(512),
                               args, 0, stream);
}

// Round 10
// 951.453 us; speedup vs baseline: 4.2195x; 4.2195x over previous
//
#include <hip/hip_runtime.h>
#include <math.h>

// Problem constants
#define BB 512
#define SS 64
#define DD 128
#define FF 256   // 2D
#define NSYM 128
#define STK 16
#define NDEPTH 8

typedef _Float16 half_t;
typedef __attribute__((ext_vector_type(4))) _Float16 half4;
typedef __attribute__((ext_vector_type(8))) _Float16 half8;
typedef __attribute__((ext_vector_type(4))) float f32x4;

// Workspace offsets (in floats)
#define Z_OFF      0ull                    // B*S*F      = 8388608
#define QKV_OFF    8388608ull              // WT32 + GT/WvT split planes
#define ZFW_OFF    33554432ull             // B*768      = 393216
#define QBUF_OFF   35651584ull             // B*16*768   = 6291456 (Q state)
#define PTR_OFF    41943040ull             // B*16       = 8192
#define ZF1_OFF    41951232ull             // B*256      = 131072
#define ZF2_OFF    42082304ull             // B*256      = 131072
#define READ_OFF   42213376ull             // B*256      = 131072
#define PROBS_OFF  42344448ull             // B*128      = 65536
#define HALT_OFF   42541056ull             // B          = 512
#define PVAL_OFF   42541568ull             // B          = 512
#define MAGP_OFF   42542592ull             // B*2        = 1024
#define MQKV_OFF   42740224ull             // 196608 floats (MTh+MTl fp16)
#define CB2_OFF    42936832ull             // 128

// ---------------------------------------------------------------------------
// Combined transposed weight, fp32: WT32[col=h*256+c][e] = W_h[e][c]
__global__ void k_buildwt32(const float* __restrict__ wr, const float* __restrict__ wi,
                            float* __restrict__ WT32) {
    int idx = blockIdx.x * 256 + threadIdx.x;   // 196608 total, grid=768
    if (idx >= 768 * 256) return;
    int col = idx >> 8;
    int e   = idx & 255;
    int h   = col >> 8;
    int c   = col & 255;
    const float* Wr = wr + h * DD * DD;
    const float* Wi = wi + h * DD * DD;
    float v;
    if (c < DD) {
        v = (e < DD) ? Wr[c * DD + e] : -Wi[c * DD + (e - DD)];
    } else {
        int j = c - DD;
        v = (e < DD) ? Wi[j * DD + e] : Wr[j * DD + (e - DD)];
    }
    WT32[idx] = v;
}

// GT[n][e] = G[e][n] = sum_c Wq[e][c]*Wk[n][c], split to fp16 h/l (unscaled).
__global__ __launch_bounds__(256) void k_buildG(const float* __restrict__ WT32,
                                                half_t* __restrict__ GTh,
                                                half_t* __restrict__ GTl) {
    __shared__ float kcol[256];
    int n = blockIdx.x;
    int e = threadIdx.x;
    kcol[e] = WT32[65536 + e * 256 + n];   // Wk[n][c=e]
    __syncthreads();
    float s = 0.f;
    for (int c = 0; c < 256; ++c) s += kcol[c] * WT32[c * 256 + e];  // Wq[e][c]
    half_t h = (half_t)s;
    GTh[n * 256 + e] = h;
    GTl[n * 256 + e] = (half_t)(s - (float)h);
}

__global__ void k_splitWv(const float* __restrict__ WT32,
                          half_t* __restrict__ WvTh, half_t* __restrict__ WvTl) {
    int idx = blockIdx.x * 256 + threadIdx.x;   // 65536, grid 256
    float v = WT32[131072 + idx];   // WvT[n][e]
    half_t h = (half_t)v;
    WvTh[idx] = h;
    WvTl[idx] = (half_t)(v - (float)h);
}

// Memory-path combined transposed split weights (fp16 h/l).
__global__ void k_buildwt(const float* __restrict__ wr, const float* __restrict__ wi,
                          half_t* __restrict__ WTh, half_t* __restrict__ WTl) {
    int idx = blockIdx.x * 256 + threadIdx.x;   // 196608 total, grid=768
    if (idx >= 768 * 256) return;
    int col = idx >> 8;
    int e   = idx & 255;
    int h   = col >> 8;
    int c   = col & 255;
    const float* Wr = wr + h * DD * DD;
    const float* Wi = wi + h * DD * DD;
    float v;
    if (c < DD) {
        v = (e < DD) ? Wr[c * DD + e] : -Wi[c * DD + (e - DD)];
    } else {
        int j = c - DD;
        v = (e < DD) ? Wi[j * DD + e] : Wr[j * DD + (e - DD)];
    }
    half_t hh = (half_t)v;
    WTh[idx] = hh;
    WTl[idx] = (half_t)(v - (float)hh);
}

__global__ void k_cb2(const float* __restrict__ cb, float* __restrict__ cb2) {
    int n = threadIdx.x;   // 128 threads
    float s = 0.f;
    for (int c = 0; c < FF; ++c) { float v = cb[n * FF + c]; s += v * v; }
    cb2[n] = s;
}

__global__ __launch_bounds__(256) void k_init(const float* __restrict__ zr_in,
                                              const float* __restrict__ zi_in,
                                              float* __restrict__ z, float* __restrict__ qbuf,
                                              float* __restrict__ ptrv,
                                              float* __restrict__ halt, float* __restrict__ acc) {
    size_t idx = (size_t)blockIdx.x * 256 + threadIdx.x;  // grid 32768 -> 8388608
    int c = (int)(idx & 255);
    size_t bs = idx >> 8;
    z[idx] = (c < DD) ? zr_in[bs * DD + c] : zi_in[bs * DD + (c - DD)];
    acc[idx] = 0.f;
    if (idx < 6291456) qbuf[idx] = 0.f;
    if (idx < 8192)  ptrv[idx] = ((idx & 15) == 0) ? 1.f : 0.f;
    if (idx < 512)   halt[idx] = 0.f;
}

// ---------------------------------------------------------------------------
// VQ body for step tau (512 threads). Ported verbatim from R9's verified
// vq_step, with global zf2/readv/pval inputs. Writes dlt[256] (= read+quant)
// and waS[0] to LDS, updates halt/probs in global. Ends with __syncthreads.
__device__ __forceinline__ void vq_body(
        int b, int tau, int tid,
        float* zfq, float* redq, float* dsum, float* gsum, float* prq,
        float* dlt, float* waS,
        const float* __restrict__ zf2g, const float* __restrict__ readv,
        float* __restrict__ probs, float* __restrict__ halt,
        const float* __restrict__ pvalg, const float* __restrict__ magp,
        const float* __restrict__ cb, const float* __restrict__ cb2,
        const float* __restrict__ adj) {
    if (tid < 256) zfq[tid] = zf2g[b * FF + tid];
    float up = 0.f;
    if (tau > 0) {
        redq[tid] = magp[2 * tid];
        __syncthreads();
        for (int off = 256; off > 0; off >>= 1) {
            if (tid < off) redq[tid] += redq[tid + off];
            __syncthreads();
        }
        float tms = redq[0];
        __syncthreads();
        redq[tid] = magp[2 * tid + 1];
        __syncthreads();
        for (int off = 256; off > 0; off >>= 1) {
            if (tid < off) redq[tid] += redq[tid + off];
            __syncthreads();
        }
        float tmsq = redq[0];
        __syncthreads();
        const float N = 4194304.f;   // B*S*D
        float mean = tms / N;
        float var = tmsq / N - mean * mean;
        float x = var / (1.f + 1e-6f);
        up = (x > 20.f) ? x : log1pf(expf(x));
    } else {
        __syncthreads();
    }

    // zz = ||zf2||^2
    redq[tid] = (tid < 256) ? zfq[tid] * zfq[tid] : 0.f;
    __syncthreads();
    for (int off = 256; off > 0; off >>= 1) {
        if (tid < off) redq[tid] += redq[tid + off];
        __syncthreads();
    }
    float zz = redq[0];
    __syncthreads();

    // dist + gb partials: n = tid>>2, part = tid&3
    {
        int n = tid >> 2, part = tid & 3;
        float dacc = 0.f;
        const float* cbn = cb + n * FF + part * 64;
        const float* zfp = zfq + part * 64;
        for (int c2 = 0; c2 < 64; c2 += 4) {
            f32x4 cv = *(const f32x4*)(cbn + c2);
            dacc += cv[0] * zfp[c2] + cv[1] * zfp[c2 + 1] + cv[2] * zfp[c2 + 2] + cv[3] * zfp[c2 + 3];
        }
        dsum[tid] = dacc;
        float gacc = 0.f;
        if (tau > 0) {
            const float* pp = probs + b * NSYM + part * 32;
            for (int k = 0; k < 32; ++k) gacc += pp[k] * adj[(part * 32 + k) * NSYM + n];
        }
        gsum[tid] = gacc;
    }
    __syncthreads();

    float vval = -1e30f;
    if (tid < 128) {
        int n = tid;
        float dot = dsum[n * 4] + dsum[n * 4 + 1] + dsum[n * 4 + 2] + dsum[n * 4 + 3];
        float dist = (zz + cb2[n] - 2.f * dot) * (1.f / 256.f);
        float dtot = dist;
        if (tau > 0) {
            float gb = gsum[n * 4] + gsum[n * 4 + 1] + gsum[n * 4 + 2] + gsum[n * 4 + 3];
            dtot = dist - 0.01f * up * (1.f / (1.f + expf(-gb)));
        }
        vval = -dtot;
        redq[tid] = vval;
    }
    __syncthreads();
    for (int off = 64; off > 0; off >>= 1) {
        if (tid < off) redq[tid] = fmaxf(redq[tid], redq[tid + off]);
        __syncthreads();
    }
    float mx = redq[0];
    __syncthreads();
    float e = 0.f;
    if (tid < 128) { e = expf(vval - mx); redq[tid] = e; }
    __syncthreads();
    for (int off = 64; off > 0; off >>= 1) {
        if (tid < off) redq[tid] += redq[tid + off];
        __syncthreads();
    }
    float se = redq[0];
    __syncthreads();
    if (tid < 128) {
        float psm = e / se;
        prq[tid] = psm;
        probs[b * NSYM + tid] = psm;
    }
    __syncthreads();

    // quant + dlt = read + quant
    {
        int c = tid & 255, part = tid >> 8;
        float q = 0.f;
        const float* cbc = cb + part * 64 * FF + c;
        for (int k = 0; k < 64; ++k) q += prq[part * 64 + k] * cbc[k * FF];
        redq[tid] = q;
    }
    __syncthreads();
    if (tid < 256) dlt[tid] = readv[b * FF + tid] + redq[tid] + redq[256 + tid];
    if (tid == 0) {
        float h = halt[b], p = pvalg[b];
        float running = (h < 0.99f) ? 1.f : 0.f;
        float w2 = (((h + p * running) >= 0.99f) ? (1.f - h) : p) * running;
        halt[b] = h + w2;
        waS[0] = w2;
    }
    __syncthreads();
}

// ---------------------------------------------------------------------------
// Fused attention step (R6/R8 body) + vq(t-1) prologue. 8 waves, 1 block/CU.
__global__ __launch_bounds__(512, 1) void k_attn8(
        float* __restrict__ z,
        const half_t* __restrict__ GTh, const half_t* __restrict__ GTl,
        const half_t* __restrict__ WvTh, const half_t* __restrict__ WvTl,
        const float* __restrict__ zf2g, const float* __restrict__ readv,
        float* __restrict__ probs, float* __restrict__ halt,
        const float* __restrict__ pvalg, const float* __restrict__ magp,
        const float* __restrict__ cb, const float* __restrict__ cb2,
        const float* __restrict__ adj,
        float* __restrict__ acc, float* __restrict__ zf1g, int t) {
    __shared__ __align__(16) char smem[159744];
    half_t* Zh = (half_t*)smem;                  // 64 x 264, 33792 B
    half_t* Zl = (half_t*)(smem + 33792);
    half_t* U0 = (half_t*)(smem + 67584);        // union: T[64][264] / VT[256][72]
    half_t* U1 = (half_t*)(smem + 104448);
    half_t* P0 = (half_t*)(smem + 141312);
    half_t* P1 = (half_t*)(smem + 150528);
    // vq scratch overlaps U region (used only before phase T writes U)
    float* F   = (float*)(smem + 67584);
    float* zfq = F;            // 256
    float* redq= F + 256;      // 512
    float* dsum= F + 768;      // 512
    float* gsum= F + 1280;     // 512
    float* prq = F + 1792;     // 128
    float* dlt = F + 1920;     // 256
    float* waS = F + 2176;     // 1

    int b = blockIdx.x, tid = threadIdx.x;
    int w = tid >> 6, lane = tid & 63;
    int l15 = lane & 15, lq = lane >> 4;
    float* zb = z + (size_t)b * (SS * FF);
    float* accb = acc + (size_t)b * (SS * FF);

    // ---- vq prologue: applies step (t-1)'s VQ/ACT; yields dlt + waS
    if (t > 0) {
        vq_body(b, t - 1, tid, zfq, redq, dsum, gsum, prq, dlt, waS,
                zf2g, readv, probs, halt, pvalg, magp, cb, cb2, adj);
    } else {
        if (tid < 256) dlt[tid] = 0.f;
        if (tid == 0) waS[0] = 0.f;
        __syncthreads();
    }
    float wa = waS[0];
    f32x4 dv = *(const f32x4*)&dlt[lane * 4];
    bool doacc = (wa != 0.0f);

    // ---- phase 0: x0 = z + 0.1*delta; deferred acc; split to LDS
#pragma unroll
    for (int it = 0; it < 8; ++it) {
        int i = w * 8 + it;
        f32x4 zv = *(const f32x4*)(zb + (size_t)i * FF + lane * 4);
        f32x4 x0;
#pragma unroll
        for (int jj = 0; jj < 4; ++jj) x0[jj] = zv[jj] + 0.1f * dv[jj];
        if (doacc) {
            f32x4 av = *(const f32x4*)(accb + (size_t)i * FF + lane * 4);
#pragma unroll
            for (int jj = 0; jj < 4; ++jj) av[jj] += wa * x0[jj];
            *(f32x4*)(accb + (size_t)i * FF + lane * 4) = av;
        }
        half4 h4, l4;
#pragma unroll
        for (int jj = 0; jj < 4; ++jj) {
            half_t h = (half_t)x0[jj];
            h4[jj] = h; l4[jj] = (half_t)(x0[jj] - (float)h);
        }
        *(half4*)&Zh[i * 264 + lane * 4] = h4;
        *(half4*)&Zl[i * 264 + lane * 4] = l4;
    }
    __syncthreads();   // sync 1: Z staged (and all dlt reads done)

    // ---- phase T: T = x0 @ G, wave w owns 32-col band.
    {
        f32x4 tac[4][2];
#pragma unroll
        for (int mt = 0; mt < 4; ++mt)
#pragma unroll
            for (int nt = 0; nt < 2; ++nt) tac[mt][nt] = (f32x4){0.f, 0.f, 0.f, 0.f};
        __builtin_amdgcn_s_setprio(1);
        for (int kt = 0; kt < 8; ++kt) {
            int kc = kt * 32 + lq * 8;
            half8 ah[4], al[4], gh[2], gl[2];
#pragma unroll
            for (int mt = 0; mt < 4; ++mt) {
                int ro = (mt * 16 + l15) * 264 + kc;
                ah[mt] = *(const half8*)&Zh[ro];
                al[mt] = *(const half8*)&Zl[ro];
            }
#pragma unroll
            for (int nt = 0; nt < 2; ++nt) {
                size_t go = (size_t)(w * 32 + nt * 16 + l15) * 256 + kc;
                gh[nt] = *(const half8*)(GTh + go);
                gl[nt] = *(const half8*)(GTl + go);
            }
#pragma unroll
            for (int mt = 0; mt < 4; ++mt)
#pragma unroll
                for (int nt = 0; nt < 2; ++nt) {
                    tac[mt][nt] = __builtin_amdgcn_mfma_f32_16x16x32_f16(ah[mt], gh[nt], tac[mt][nt], 0, 0, 0);
                    tac[mt][nt] = __builtin_amdgcn_mfma_f32_16x16x32_f16(ah[mt], gl[nt], tac[mt][nt], 0, 0, 0);
                    tac[mt][nt] = __builtin_amdgcn_mfma_f32_16x16x32_f16(al[mt], gh[nt], tac[mt][nt], 0, 0, 0);
                }
        }
        __builtin_amdgcn_s_setprio(0);
        const float scale = 0.08838834764831845f;
#pragma unroll
        for (int mt = 0; mt < 4; ++mt)
#pragma unroll
            for (int nt = 0; nt < 2; ++nt)
#pragma unroll
                for (int r = 0; r < 4; ++r) {
                    int m = mt * 16 + lq * 4 + r;
                    int n = w * 32 + nt * 16 + l15;
                    float v = tac[mt][nt][r] * scale;
                    half_t h = (half_t)v;
                    U0[m * 264 + n] = h;
                    U1[m * 264 + n] = (half_t)(v - (float)h);
                }
    }
    __syncthreads();   // sync 2: T ready

    // ---- phase B: waves 0-3: S/softmax/P; all waves: V band.
    if (w < 4) {
        f32x4 sac[4];
#pragma unroll
        for (int jt = 0; jt < 4; ++jt) sac[jt] = (f32x4){0.f, 0.f, 0.f, 0.f};
        __builtin_amdgcn_s_setprio(1);
        for (int kt = 0; kt < 8; ++kt) {
            int kc = kt * 32 + lq * 8;
            int to = (w * 16 + l15) * 264 + kc;
            half8 bh = *(const half8*)&U0[to];
            half8 bl = *(const half8*)&U1[to];
            half8 ah[4], al[4];
#pragma unroll
            for (int jt = 0; jt < 4; ++jt) {
                int ro = (jt * 16 + l15) * 264 + kc;
                ah[jt] = *(const half8*)&Zh[ro];
                al[jt] = *(const half8*)&Zl[ro];
            }
#pragma unroll
            for (int jt = 0; jt < 4; ++jt) {
                sac[jt] = __builtin_amdgcn_mfma_f32_16x16x32_f16(ah[jt], bh, sac[jt], 0, 0, 0);
                sac[jt] = __builtin_amdgcn_mfma_f32_16x16x32_f16(ah[jt], bl, sac[jt], 0, 0, 0);
                sac[jt] = __builtin_amdgcn_mfma_f32_16x16x32_f16(al[jt], bh, sac[jt], 0, 0, 0);
            }
        }
        __builtin_amdgcn_s_setprio(0);
        float sv[4][4];
        float mx = -1e30f;
#pragma unroll
        for (int jt = 0; jt < 4; ++jt)
#pragma unroll
            for (int r = 0; r < 4; ++r) { sv[jt][r] = sac[jt][r]; mx = fmaxf(mx, sv[jt][r]); }
        mx = fmaxf(mx, __shfl_xor(mx, 16));
        mx = fmaxf(mx, __shfl_xor(mx, 32));
        float ssum = 0.f;
#pragma unroll
        for (int jt = 0; jt < 4; ++jt)
#pragma unroll
            for (int r = 0; r < 4; ++r) { float e = expf(sv[jt][r] - mx); sv[jt][r] = e; ssum += e; }
        ssum += __shfl_xor(ssum, 16);
        ssum += __shfl_xor(ssum, 32);
        float inv = 1.f / ssum;
#pragma unroll
        for (int jt = 0; jt < 4; ++jt) {
            half4 h4, l4;
#pragma unroll
            for (int r = 0; r < 4; ++r) {
                float pv = sv[jt][r] * inv;
                half_t hh = (half_t)pv;
                h4[r] = hh;
                l4[r] = (half_t)(pv - (float)hh);
            }
            *(half4*)&P0[w * 1152 + l15 * 72 + jt * 16 + lq * 4] = h4;
            *(half4*)&P1[w * 1152 + l15 * 72 + jt * 16 + lq * 4] = l4;
        }
    }

    f32x4 vac[4][2];
#pragma unroll
    for (int mt = 0; mt < 4; ++mt)
#pragma unroll
        for (int nt = 0; nt < 2; ++nt) vac[mt][nt] = (f32x4){0.f, 0.f, 0.f, 0.f};
    __builtin_amdgcn_s_setprio(1);
    for (int kt = 0; kt < 8; ++kt) {
        int kc = kt * 32 + lq * 8;
        half8 ah[4], al[4], gh[2], gl[2];
#pragma unroll
        for (int mt = 0; mt < 4; ++mt) {
            int ro = (mt * 16 + l15) * 264 + kc;
            ah[mt] = *(const half8*)&Zh[ro];
            al[mt] = *(const half8*)&Zl[ro];
        }
#pragma unroll
        for (int nt = 0; nt < 2; ++nt) {
            size_t go = (size_t)(w * 32 + nt * 16 + l15) * 256 + kc;
            gh[nt] = *(const half8*)(WvTh + go);
            gl[nt] = *(const half8*)(WvTl + go);
        }
#pragma unroll
        for (int mt = 0; mt < 4; ++mt)
#pragma unroll
            for (int nt = 0; nt < 2; ++nt) {
                vac[mt][nt] = __builtin_amdgcn_mfma_f32_16x16x32_f16(ah[mt], gh[nt], vac[mt][nt], 0, 0, 0);
                vac[mt][nt] = __builtin_amdgcn_mfma_f32_16x16x32_f16(ah[mt], gl[nt], vac[mt][nt], 0, 0, 0);
                vac[mt][nt] = __builtin_amdgcn_mfma_f32_16x16x32_f16(al[mt], gh[nt], vac[mt][nt], 0, 0, 0);
            }
    }
    __builtin_amdgcn_s_setprio(0);
    __syncthreads();   // sync 3: S done reading T

    // VT write
#pragma unroll
    for (int mt = 0; mt < 4; ++mt)
#pragma unroll
        for (int nt = 0; nt < 2; ++nt) {
            int n = w * 32 + nt * 16 + l15;
            int m0 = mt * 16 + lq * 4;
            half4 h4, l4;
#pragma unroll
            for (int r = 0; r < 4; ++r) {
                float v = vac[mt][nt][r];
                half_t h = (half_t)v;
                h4[r] = h; l4[r] = (half_t)(v - (float)h);
            }
            *(half4*)&U0[n * 72 + m0] = h4;
            *(half4*)&U1[n * 72 + m0] = l4;
        }
    __syncthreads();   // sync 4: VT + P visible

    // ---- phase O
    f32x4 oc[4][2];
#pragma unroll
    for (int mt = 0; mt < 4; ++mt)
#pragma unroll
        for (int nt = 0; nt < 2; ++nt) oc[mt][nt] = (f32x4){0.f, 0.f, 0.f, 0.f};
    __builtin_amdgcn_s_setprio(1);
#pragma unroll
    for (int kt = 0; kt < 2; ++kt) {
        half8 pah[4], pal[4];
#pragma unroll
        for (int mt = 0; mt < 4; ++mt) {
            int po = l15 * 72 + kt * 32 + lq * 8;
            pah[mt] = *(const half8*)&P0[mt * 1152 + po];
            pal[mt] = *(const half8*)&P1[mt * 1152 + po];
        }
#pragma unroll
        for (int nt = 0; nt < 2; ++nt) {
            int n = w * 32 + nt * 16 + l15;
            half8 vbh = *(const half8*)&U0[n * 72 + kt * 32 + lq * 8];
            half8 vbl = *(const half8*)&U1[n * 72 + kt * 32 + lq * 8];
#pragma unroll
            for (int mt = 0; mt < 4; ++mt) {
                oc[mt][nt] = __builtin_amdgcn_mfma_f32_16x16x32_f16(pah[mt], vbh, oc[mt][nt], 0, 0, 0);
                oc[mt][nt] = __builtin_amdgcn_mfma_f32_16x16x32_f16(pah[mt], vbl, oc[mt][nt], 0, 0, 0);
                oc[mt][nt] = __builtin_amdgcn_mfma_f32_16x16x32_f16(pal[mt], vbh, oc[mt][nt], 0, 0, 0);
            }
        }
    }
    __builtin_amdgcn_s_setprio(0);

    // ---- epilogue: z_out = O + 0.1*x0; zf1 col-means for this wave's band
    float zfs[2] = {0.f, 0.f};
#pragma unroll
    for (int mt = 0; mt < 4; ++mt)
#pragma unroll
        for (int nt = 0; nt < 2; ++nt)
#pragma unroll
            for (int r = 0; r < 4; ++r) {
                int i = mt * 16 + lq * 4 + r;
                int c = w * 32 + nt * 16 + l15;
                int zo = i * 264 + c;
                float x0 = (float)Zh[zo] + (float)Zl[zo];
                float z1 = oc[mt][nt][r] + 0.1f * x0;
                zb[(size_t)i * FF + c] = z1;
                zfs[nt] += z1;
            }
#pragma unroll
    for (int nt = 0; nt < 2; ++nt) {
        zfs[nt] += __shfl_xor(zfs[nt], 16);
        zfs[nt] += __shfl_xor(zfs[nt], 32);
    }
    if (lq == 0) {
#pragma unroll
        for (int nt = 0; nt < 2; ++nt)
            zf1g[b * FF + w * 32 + nt * 16 + l15] = zfs[nt] * (1.f / 64.f);
    }
}

// ---------------------------------------------------------------------------
// Split-fp16 MFMA GEMM: C[M][768] = A[M][256] @ W[256][768].  Used for zfW.
__global__ __launch_bounds__(256) void gemm_split(const float* __restrict__ A,
                                                  const half_t* __restrict__ WTh,
                                                  const half_t* __restrict__ WTl,
                                                  float* __restrict__ C) {
    __shared__ float As[128][36];
    int bm = blockIdx.x / 6;
    int bn = blockIdx.x % 6;
    int tid = threadIdx.x;
    int w = tid >> 6;
    int lane = tid & 63;
    int wr = w >> 1, wc = w & 1;
    int l15 = lane & 15;
    int lq  = lane >> 4;

    f32x4 acc[4][4];
#pragma unroll
    for (int i = 0; i < 4; ++i)
#pragma unroll
        for (int j = 0; j < 4; ++j) acc[i][j] = (f32x4){0.f, 0.f, 0.f, 0.f};

    const float* Ablk = A + (size_t)bm * 128 * 256;
    int colbase = bn * 128 + wc * 64;

    int srow = tid >> 1;
    int sseg = (tid & 1) * 16;

    for (int k0 = 0; k0 < 256; k0 += 32) {
        __syncthreads();
        {
            const float* src = Ablk + (size_t)srow * 256 + k0 + sseg;
            f32x4 v0 = *(const f32x4*)(src);
            f32x4 v1 = *(const f32x4*)(src + 4);
            f32x4 v2 = *(const f32x4*)(src + 8);
            f32x4 v3 = *(const f32x4*)(src + 12);
            *(f32x4*)&As[srow][sseg]      = v0;
            *(f32x4*)&As[srow][sseg + 4]  = v1;
            *(f32x4*)&As[srow][sseg + 8]  = v2;
            *(f32x4*)&As[srow][sseg + 12] = v3;
        }
        __syncthreads();

        half8 bh[4], bl[4];
#pragma unroll
        for (int tj = 0; tj < 4; ++tj) {
            size_t off = (size_t)(colbase + tj * 16 + l15) * 256 + k0 + lq * 8;
            bh[tj] = *(const half8*)(WTh + off);
            bl[tj] = *(const half8*)(WTl + off);
        }

        half8 ah[4], al[4];
#pragma unroll
        for (int ti = 0; ti < 4; ++ti) {
            const float* ap = &As[wr * 64 + ti * 16 + l15][lq * 8];
            f32x4 a0 = *(const f32x4*)(ap);
            f32x4 a1 = *(const f32x4*)(ap + 4);
#pragma unroll
            for (int j = 0; j < 4; ++j) {
                float x = a0[j];
                half_t h = (half_t)x;
                ah[ti][j] = h;
                al[ti][j] = (half_t)(x - (float)h);
            }
#pragma unroll
            for (int j = 0; j < 4; ++j) {
                float x = a1[j];
                half_t h = (half_t)x;
                ah[ti][4 + j] = h;
                al[ti][4 + j] = (half_t)(x - (float)h);
            }
        }

#pragma unroll
        for (int ti = 0; ti < 4; ++ti)
#pragma unroll
            for (int tj = 0; tj < 4; ++tj)
                acc[ti][tj] = __builtin_amdgcn_mfma_f32_16x16x32_f16(ah[ti], bh[tj], acc[ti][tj], 0, 0, 0);
#pragma unroll
        for (int ti = 0; ti < 4; ++ti)
#pragma unroll
            for (int tj = 0; tj < 4; ++tj)
                acc[ti][tj] = __builtin_amdgcn_mfma_f32_16x16x32_f16(ah[ti], bl[tj], acc[ti][tj], 0, 0, 0);
#pragma unroll
        for (int ti = 0; ti < 4; ++ti)
#pragma unroll
            for (int tj = 0; tj < 4; ++tj)
                acc[ti][tj] = __builtin_amdgcn_mfma_f32_16x16x32_f16(al[ti], bh[tj], acc[ti][tj], 0, 0, 0);
    }

    float* Cb = C + (size_t)(bm * 128 + wr * 64) * 768 + bn * 128 + wc * 64;
#pragma unroll
    for (int ti = 0; ti < 4; ++ti)
#pragma unroll
        for (int tj = 0; tj < 4; ++tj) {
            int r0 = ti * 16 + lq * 4;
            int c0 = tj * 16 + l15;
#pragma unroll
            for (int r = 0; r < 4; ++r)
                Cb[(size_t)(r0 + r) * 768 + c0] = acc[ti][tj][r];
        }
}

// ---------------------------------------------------------------------------
// Stack step + mag: gate -> ptr -> Q=(1-push)Q+push*zfW -> memattn -> read ->
// zf2/pval -> mag partials. One block (4 waves)/batch, 256 threads.
__global__ __launch_bounds__(256, 2) void k_stack2(
        const float* __restrict__ zf1,
        const float* __restrict__ ctrl_w, const float* __restrict__ ctrl_b,
        float* __restrict__ ptrv, float* __restrict__ qbuf,
        const float* __restrict__ zfW,
        float* __restrict__ readv, float* __restrict__ zf2,
        const float* __restrict__ halt_w, const float* __restrict__ halt_b,
        float* __restrict__ pval,
        const float* __restrict__ z, float* __restrict__ magpart) {
    __shared__ float zf[256];
    __shared__ float g[3];
    __shared__ float oldp[16], np[16];
    __shared__ float Q[16][780];          // stride 780: 2-way (free) bank profile
    __shared__ float sm[16][17];
    __shared__ float rowmax[16], rowsum[16], pw[16];
    __shared__ float rd[256];
    __shared__ float red[256];

    int b = blockIdx.x, tid = threadIdx.x;
    int w = tid >> 6, lane = tid & 63;

    // 1. gates from zf1
    zf[tid] = zf1[b * FF + tid];
    if (tid < 16) oldp[tid] = ptrv[b * STK + tid];
    __syncthreads();
    if (w < 3) {
        float s = 0.f;
#pragma unroll
        for (int q = 0; q < 4; ++q) {
            int c = lane + 64 * q;
            s += zf[c] * ctrl_w[c * 3 + w];
        }
#pragma unroll
        for (int off = 1; off < 64; off <<= 1) s += __shfl_xor(s, off);
        if (lane == 0) g[w] = 1.f / (1.f + expf(-(s + ctrl_b[w])));
    }
    __syncthreads();
    float tot = g[0] + g[1] + g[2] + 1e-6f;
    float push = g[0] / tot, pop = g[1] / tot, stay = g[2] / tot;
    if (tid < 16) {
        float v = push * oldp[(tid + 15) & 15] + pop * oldp[(tid + 1) & 15] + stay * oldp[tid];
        np[tid] = v;
        ptrv[b * STK + tid] = v;
    }

    // 2. Q recurrence: Q = (1-push)*Q + push*zfW[b]
    float omp = 1.f - push;
    float zw0 = push * zfW[b * 768 + tid];
    float zw1 = push * zfW[b * 768 + 256 + tid];
    float zw2 = push * zfW[b * 768 + 512 + tid];
    float* qb = qbuf + (size_t)b * (STK * 768);
#pragma unroll 4
    for (int t16 = 0; t16 < 16; ++t16) {
        float q0 = qb[t16 * 768 + tid]       * omp + zw0;
        float q1 = qb[t16 * 768 + 256 + tid] * omp + zw1;
        float q2 = qb[t16 * 768 + 512 + tid] * omp + zw2;
        qb[t16 * 768 + tid]       = q0;
        qb[t16 * 768 + 256 + tid] = q1;
        qb[t16 * 768 + 512 + tid] = q2;
        Q[t16][tid] = q0;
        Q[t16][256 + tid] = q1;
        Q[t16][512 + tid] = q2;
    }
    __syncthreads();

    // 3. memattn
    {
        int i = tid >> 4, j = tid & 15;
        float s = 0.f;
#pragma unroll 4
        for (int c = 0; c < 256; c += 4) {
            f32x4 qi = *(const f32x4*)&Q[i][c];
            f32x4 kj = *(const f32x4*)&Q[j][256 + c];
            s += qi[0] * kj[0] + qi[1] * kj[1] + qi[2] * kj[2] + qi[3] * kj[3];
        }
        s *= 0.08838834764831845f;
        sm[i][j] = s;
        __syncthreads();
        if (tid < 16) {
            float m = -1e30f;
            for (int jj = 0; jj < 16; ++jj) m = fmaxf(m, sm[tid][jj]);
            float su = 0.f;
            for (int jj = 0; jj < 16; ++jj) su += expf(sm[tid][jj] - m);
            rowmax[tid] = m; rowsum[tid] = su;
        }
        __syncthreads();
        float p = expf(s - rowmax[i]) / rowsum[i];
        sm[i][j] = p;
        __syncthreads();
        if (tid < 16) {
            float a = 0.f;
            for (int s2 = 0; s2 < 16; ++s2) a += np[s2] * sm[s2][tid];
            pw[tid] = a;
        }
        __syncthreads();
    }

    // 4. read + zf2 + pval
    {
        float a = 0.f;
#pragma unroll
        for (int jj = 0; jj < 16; ++jj) a += pw[jj] * Q[jj][512 + tid];
        rd[tid] = a;
        readv[b * FF + tid] = a;
        float z2 = zf[tid] + 0.1f * a;
        zf2[b * FF + tid] = z2;
        red[tid] = z2 * halt_w[tid];
        __syncthreads();
        for (int off = 128; off > 0; off >>= 1) {
            if (tid < off) red[tid] += red[tid + off];
            __syncthreads();
        }
        if (tid == 0) pval[b] = 1.f / (1.f + expf(-(red[0] + halt_b[0])));
        __syncthreads();
    }

    // 5. mag sweep over z1 (+0.1*read)  [R7-verified block]
    {
        int d = tid & 127, hf = tid >> 7;
        float rr = 0.1f * rd[d];
        float ri = 0.1f * rd[DD + d];
        const float* zb = z + (size_t)b * (SS * FF);
        float ms = 0.f, msq = 0.f;
        for (int s32 = 0; s32 < 32; ++s32) {
            int s = hf * 32 + s32;
            float zr = zb[s * FF + d] + rr;
            float zi = zb[s * FF + DD + d] + ri;
            float m2 = zr * zr + zi * zi;
            ms += sqrtf(m2); msq += m2;
        }
        red[tid] = ms;
        __syncthreads();
        for (int off = 128; off > 0; off >>= 1) {
            if (tid < off) red[tid] += red[tid + off];
            __syncthreads();
        }
        float tms = red[0];
        __syncthreads();
        red[tid] = msq;
        __syncthreads();
        for (int off = 128; off > 0; off >>= 1) {
            if (tid < off) red[tid] += red[tid + off];
            __syncthreads();
        }
        if (tid == 0) { magpart[2 * b] = tms; magpart[2 * b + 1] = red[0]; }
    }
}

// ---------------------------------------------------------------------------
// Final: vq(DEPTH-1) + ACT accumulation into acc.  512 blocks x 512 thr.
__global__ __launch_bounds__(512) void k_vqepi(
        const float* __restrict__ z,
        const float* __restrict__ zf2g, const float* __restrict__ readv,
        float* __restrict__ probs, float* __restrict__ halt,
        const float* __restrict__ pvalg, const float* __restrict__ magp,
        const float* __restrict__ cb, const float* __restrict__ cb2,
        const float* __restrict__ adj, float* __restrict__ acc) {
    __shared__ float zfq[256], redq[512], dsum[512], gsum[512], prq[128], dlt[256], waS[1];
    int b = blockIdx.x, tid = threadIdx.x;
    vq_body(b, NDEPTH - 1, tid, zfq, redq, dsum, gsum, prq, dlt, waS,
            zf2g, readv, probs, halt, pvalg, magp, cb, cb2, adj);
    float wa = waS[0];
    if (wa != 0.0f) {
        for (int i = tid; i < SS * FF; i += 512) {
            int c = i & 255;
            size_t gi = (size_t)b * (SS * FF) + i;
            acc[gi] += wa * (z[gi] + 0.1f * dlt[c]);
        }
    }
}

// ---------------------------------------------------------------------------
extern "C" void kernel_launch(void* const* d_in, const int* in_sizes, int n_in,
                              void* d_out, int out_size, void* d_ws, size_t ws_size,
                              hipStream_t stream) {
    const float* z_real  = (const float*)d_in[0];
    const float* z_imag  = (const float*)d_in[1];
    const float* attn_wr = (const float*)d_in[2];
    const float* attn_wi = (const float*)d_in[3];
    const float* mem_wr  = (const float*)d_in[4];
    const float* mem_wi  = (const float*)d_in[5];
    const float* ctrl_w  = (const float*)d_in[6];
    const float* ctrl_b  = (const float*)d_in[7];
    const float* halt_w  = (const float*)d_in[8];
    const float* halt_b  = (const float*)d_in[9];
    const float* codebook  = (const float*)d_in[10];
    const float* adjacency = (const float*)d_in[11];

    float* ws = (float*)d_ws;
    float* z      = ws + Z_OFF;
    float* WT32   = ws + QKV_OFF;
    half_t* GTh   = (half_t*)(ws + QKV_OFF + 196608);
    half_t* GTl   = GTh + 65536;
    half_t* WvTh  = GTl + 65536;
    half_t* WvTl  = WvTh + 65536;
    float* zfW    = ws + ZFW_OFF;
    float* qbuf   = ws + QBUF_OFF;
    float* ptrv   = ws + PTR_OFF;
    float* zf1    = ws + ZF1_OFF;
    float* zf2    = ws + ZF2_OFF;
    float* readv  = ws + READ_OFF;
    float* probs  = ws + PROBS_OFF;
    float* halt   = ws + HALT_OFF;
    float* pval   = ws + PVAL_OFF;
    float* magp   = ws + MAGP_OFF;
    half_t* MTh   = (half_t*)(ws + MQKV_OFF);
    half_t* MTl   = (half_t*)(ws + MQKV_OFF) + 196608;
    float* cb2    = ws + CB2_OFF;
    float* acc    = (float*)d_out;

    k_buildwt32<<<768, 256, 0, stream>>>(attn_wr, attn_wi, WT32);
    k_buildG<<<256, 256, 0, stream>>>(WT32, GTh, GTl);
    k_splitWv<<<256, 256, 0, stream>>>(WT32, WvTh, WvTl);
    k_buildwt<<<768, 256, 0, stream>>>(mem_wr, mem_wi, MTh, MTl);
    k_cb2<<<1, 128, 0, stream>>>(codebook, cb2);
    k_init<<<32768, 256, 0, stream>>>(z_real, z_imag, z, qbuf, ptrv, halt, acc);

    for (int t = 0; t < NDEPTH; ++t) {
        k_attn8<<<BB, 512, 0, stream>>>(z, GTh, GTl, WvTh, WvTl,
                                        zf2, readv, probs, halt, pval, magp,
                                        codebook, cb2, adjacency, acc, zf1, t);
        gemm_split<<<(BB / 128) * 6, 256, 0, stream>>>(zf1, MTh, MTl, zfW);   // 24 blocks
        k_stack2<<<BB, 256, 0, stream>>>(zf1, ctrl_w, ctrl_b, ptrv, qbuf, zfW,
                                         readv, zf2, halt_w, halt_b, pval, z, magp);
    }
    k_vqepi<<<BB, 512, 0, stream>>>(z, zf2, readv, probs, halt, pval, magp,
                                    codebook, cb2, adjacency, acc);
}

// Round 11
// 917.540 us; speedup vs baseline: 4.3755x; 1.0370x over previous
//
#include <hip/hip_runtime.h>
#include <math.h>

// Problem constants
#define BB 512
#define SS 64
#define DD 128
#define FF 256   // 2D
#define NSYM 128
#define STK 16
#define NDEPTH 8

typedef _Float16 half_t;
typedef __attribute__((ext_vector_type(4))) _Float16 half4;
typedef __attribute__((ext_vector_type(8))) _Float16 half8;
typedef __attribute__((ext_vector_type(4))) float f32x4;

// Workspace offsets (in floats)
#define Z_OFF      0ull                    // B*S*F      = 8388608
#define QKV_OFF    8388608ull              // WT32 + GT/WvT split planes
#define ZFW_OFF    33554432ull             // B*768      = 393216
#define QBUF_OFF   35651584ull             // B*16*768   = 6291456 (Q state)
#define PTR_OFF    41943040ull             // B*16       = 8192
#define ZF1_OFF    41951232ull             // B*256      = 131072
#define ZF2_OFF    42082304ull             // B*256      = 131072
#define READ_OFF   42213376ull             // B*256      = 131072
#define PROBS_OFF  42344448ull             // B*128      = 65536
#define DELTA_OFF  42409984ull             // B*256      = 131072 (read + quant)
#define HALT_OFF   42541056ull             // B          = 512
#define PVAL_OFF   42541568ull             // B          = 512
#define WACT_OFF   42542080ull             // B          = 512
#define MAGP_OFF   42542592ull             // B*2        = 1024
#define MQKV_OFF   42740224ull             // 196608 floats (MTh+MTl fp16)
#define CB2_OFF    42936832ull             // 128

// ---------------------------------------------------------------------------
// Combined transposed weight, fp32: WT32[col=h*256+c][e] = W_h[e][c]
__global__ void k_buildwt32(const float* __restrict__ wr, const float* __restrict__ wi,
                            float* __restrict__ WT32) {
    int idx = blockIdx.x * 256 + threadIdx.x;   // 196608 total, grid=768
    if (idx >= 768 * 256) return;
    int col = idx >> 8;
    int e   = idx & 255;
    int h   = col >> 8;
    int c   = col & 255;
    const float* Wr = wr + h * DD * DD;
    const float* Wi = wi + h * DD * DD;
    float v;
    if (c < DD) {
        v = (e < DD) ? Wr[c * DD + e] : -Wi[c * DD + (e - DD)];
    } else {
        int j = c - DD;
        v = (e < DD) ? Wi[j * DD + e] : Wr[j * DD + (e - DD)];
    }
    WT32[idx] = v;
}

// GT[n][e] = G[e][n] = sum_c Wq[e][c]*Wk[n][c], split to fp16 h/l (unscaled).
__global__ __launch_bounds__(256) void k_buildG(const float* __restrict__ WT32,
                                                half_t* __restrict__ GTh,
                                                half_t* __restrict__ GTl) {
    __shared__ float kcol[256];
    int n = blockIdx.x;
    int e = threadIdx.x;
    kcol[e] = WT32[65536 + e * 256 + n];   // Wk[n][c=e]
    __syncthreads();
    float s = 0.f;
    for (int c = 0; c < 256; ++c) s += kcol[c] * WT32[c * 256 + e];  // Wq[e][c]
    half_t h = (half_t)s;
    GTh[n * 256 + e] = h;
    GTl[n * 256 + e] = (half_t)(s - (float)h);
}

__global__ void k_splitWv(const float* __restrict__ WT32,
                          half_t* __restrict__ WvTh, half_t* __restrict__ WvTl) {
    int idx = blockIdx.x * 256 + threadIdx.x;   // 65536, grid 256
    float v = WT32[131072 + idx];   // WvT[n][e]
    half_t h = (half_t)v;
    WvTh[idx] = h;
    WvTl[idx] = (half_t)(v - (float)h);
}

// Memory-path combined transposed split weights (fp16 h/l).
__global__ void k_buildwt(const float* __restrict__ wr, const float* __restrict__ wi,
                          half_t* __restrict__ WTh, half_t* __restrict__ WTl) {
    int idx = blockIdx.x * 256 + threadIdx.x;   // 196608 total, grid=768
    if (idx >= 768 * 256) return;
    int col = idx >> 8;
    int e   = idx & 255;
    int h   = col >> 8;
    int c   = col & 255;
    const float* Wr = wr + h * DD * DD;
    const float* Wi = wi + h * DD * DD;
    float v;
    if (c < DD) {
        v = (e < DD) ? Wr[c * DD + e] : -Wi[c * DD + (e - DD)];
    } else {
        int j = c - DD;
        v = (e < DD) ? Wi[j * DD + e] : Wr[j * DD + (e - DD)];
    }
    half_t hh = (half_t)v;
    WTh[idx] = hh;
    WTl[idx] = (half_t)(v - (float)hh);
}

__global__ void k_cb2(const float* __restrict__ cb, float* __restrict__ cb2) {
    int n = threadIdx.x;   // 128 threads
    float s = 0.f;
    for (int c = 0; c < FF; ++c) { float v = cb[n * FF + c]; s += v * v; }
    cb2[n] = s;
}

__global__ __launch_bounds__(256) void k_init(const float* __restrict__ zr_in,
                                              const float* __restrict__ zi_in,
                                              float* __restrict__ z, float* __restrict__ qbuf,
                                              float* __restrict__ ptrv,
                                              float* __restrict__ halt, float* __restrict__ acc,
                                              float* __restrict__ delta, float* __restrict__ wact) {
    size_t idx = (size_t)blockIdx.x * 256 + threadIdx.x;  // grid 32768 -> 8388608
    int c = (int)(idx & 255);
    size_t bs = idx >> 8;
    z[idx] = (c < DD) ? zr_in[bs * DD + c] : zi_in[bs * DD + (c - DD)];
    acc[idx] = 0.f;
    if (idx < 6291456) qbuf[idx] = 0.f;
    if (idx < 131072) delta[idx] = 0.f;
    if (idx < 8192)  ptrv[idx] = ((idx & 15) == 0) ? 1.f : 0.f;
    if (idx < 512)   { halt[idx] = 0.f; wact[idx] = 0.f; }
}

// ---------------------------------------------------------------------------
// Fused attention step (lean R8 body + setprio + kt unroll). 8 waves, 1 blk/CU.
__global__ __launch_bounds__(512, 1) void k_attn8(
        float* __restrict__ z,
        const half_t* __restrict__ GTh, const half_t* __restrict__ GTl,
        const half_t* __restrict__ WvTh, const half_t* __restrict__ WvTl,
        const float* __restrict__ delta, const float* __restrict__ wact,
        float* __restrict__ acc, float* __restrict__ zf1g) {
    __shared__ half_t Zh[16896];         // 64 x 264, 33 KB
    __shared__ half_t Zl[16896];
    __shared__ half_t Ubuf[2][18432];    // union: T[64][264] / VT[256][72]
    __shared__ half_t Pbuf[2][4][1152];

    int b = blockIdx.x, tid = threadIdx.x;
    int w = tid >> 6, lane = tid & 63;
    int l15 = lane & 15, lq = lane >> 4;
    float* zb = z + (size_t)b * (SS * FF);
    float* accb = acc + (size_t)b * (SS * FF);

    // ---- phase 0: x0 = z + 0.1*delta; deferred acc; split to LDS
    float wa = wact[b];
    f32x4 dv = *(const f32x4*)(delta + b * FF + lane * 4);
    bool doacc = (wa != 0.0f);
#pragma unroll
    for (int it = 0; it < 8; ++it) {
        int i = w * 8 + it;
        f32x4 zv = *(const f32x4*)(zb + (size_t)i * FF + lane * 4);
        f32x4 x0;
#pragma unroll
        for (int jj = 0; jj < 4; ++jj) x0[jj] = zv[jj] + 0.1f * dv[jj];
        if (doacc) {
            f32x4 av = *(const f32x4*)(accb + (size_t)i * FF + lane * 4);
#pragma unroll
            for (int jj = 0; jj < 4; ++jj) av[jj] += wa * x0[jj];
            *(f32x4*)(accb + (size_t)i * FF + lane * 4) = av;
        }
        half4 h4, l4;
#pragma unroll
        for (int jj = 0; jj < 4; ++jj) {
            half_t h = (half_t)x0[jj];
            h4[jj] = h; l4[jj] = (half_t)(x0[jj] - (float)h);
        }
        *(half4*)&Zh[i * 264 + lane * 4] = h4;
        *(half4*)&Zl[i * 264 + lane * 4] = l4;
    }
    __syncthreads();   // sync 1: Z staged

    // ---- phase T: T = x0 @ G, wave w owns 32-col band.
    {
        f32x4 tac[4][2];
#pragma unroll
        for (int mt = 0; mt < 4; ++mt)
#pragma unroll
            for (int nt = 0; nt < 2; ++nt) tac[mt][nt] = (f32x4){0.f, 0.f, 0.f, 0.f};
        __builtin_amdgcn_s_setprio(1);
#pragma unroll 2
        for (int kt = 0; kt < 8; ++kt) {
            int kc = kt * 32 + lq * 8;
            half8 ah[4], al[4], gh[2], gl[2];
#pragma unroll
            for (int mt = 0; mt < 4; ++mt) {
                int ro = (mt * 16 + l15) * 264 + kc;
                ah[mt] = *(const half8*)&Zh[ro];
                al[mt] = *(const half8*)&Zl[ro];
            }
#pragma unroll
            for (int nt = 0; nt < 2; ++nt) {
                size_t go = (size_t)(w * 32 + nt * 16 + l15) * 256 + kc;
                gh[nt] = *(const half8*)(GTh + go);
                gl[nt] = *(const half8*)(GTl + go);
            }
#pragma unroll
            for (int mt = 0; mt < 4; ++mt)
#pragma unroll
                for (int nt = 0; nt < 2; ++nt) {
                    tac[mt][nt] = __builtin_amdgcn_mfma_f32_16x16x32_f16(ah[mt], gh[nt], tac[mt][nt], 0, 0, 0);
                    tac[mt][nt] = __builtin_amdgcn_mfma_f32_16x16x32_f16(ah[mt], gl[nt], tac[mt][nt], 0, 0, 0);
                    tac[mt][nt] = __builtin_amdgcn_mfma_f32_16x16x32_f16(al[mt], gh[nt], tac[mt][nt], 0, 0, 0);
                }
        }
        __builtin_amdgcn_s_setprio(0);
        const float scale = 0.08838834764831845f;
#pragma unroll
        for (int mt = 0; mt < 4; ++mt)
#pragma unroll
            for (int nt = 0; nt < 2; ++nt)
#pragma unroll
                for (int r = 0; r < 4; ++r) {
                    int m = mt * 16 + lq * 4 + r;
                    int n = w * 32 + nt * 16 + l15;
                    float v = tac[mt][nt][r] * scale;
                    half_t h = (half_t)v;
                    Ubuf[0][m * 264 + n] = h;
                    Ubuf[1][m * 264 + n] = (half_t)(v - (float)h);
                }
    }
    __syncthreads();   // sync 2: T ready

    // ---- phase B: waves 0-3: S/softmax/P; all waves: V band.
    if (w < 4) {
        f32x4 sac[4];
#pragma unroll
        for (int jt = 0; jt < 4; ++jt) sac[jt] = (f32x4){0.f, 0.f, 0.f, 0.f};
        __builtin_amdgcn_s_setprio(1);
#pragma unroll 2
        for (int kt = 0; kt < 8; ++kt) {
            int kc = kt * 32 + lq * 8;
            int to = (w * 16 + l15) * 264 + kc;
            half8 bh = *(const half8*)&Ubuf[0][to];
            half8 bl = *(const half8*)&Ubuf[1][to];
            half8 ah[4], al[4];
#pragma unroll
            for (int jt = 0; jt < 4; ++jt) {
                int ro = (jt * 16 + l15) * 264 + kc;
                ah[jt] = *(const half8*)&Zh[ro];
                al[jt] = *(const half8*)&Zl[ro];
            }
#pragma unroll
            for (int jt = 0; jt < 4; ++jt) {
                sac[jt] = __builtin_amdgcn_mfma_f32_16x16x32_f16(ah[jt], bh, sac[jt], 0, 0, 0);
                sac[jt] = __builtin_amdgcn_mfma_f32_16x16x32_f16(ah[jt], bl, sac[jt], 0, 0, 0);
                sac[jt] = __builtin_amdgcn_mfma_f32_16x16x32_f16(al[jt], bh, sac[jt], 0, 0, 0);
            }
        }
        __builtin_amdgcn_s_setprio(0);
        float sv[4][4];
        float mx = -1e30f;
#pragma unroll
        for (int jt = 0; jt < 4; ++jt)
#pragma unroll
            for (int r = 0; r < 4; ++r) { sv[jt][r] = sac[jt][r]; mx = fmaxf(mx, sv[jt][r]); }
        mx = fmaxf(mx, __shfl_xor(mx, 16));
        mx = fmaxf(mx, __shfl_xor(mx, 32));
        float ssum = 0.f;
#pragma unroll
        for (int jt = 0; jt < 4; ++jt)
#pragma unroll
            for (int r = 0; r < 4; ++r) { float e = expf(sv[jt][r] - mx); sv[jt][r] = e; ssum += e; }
        ssum += __shfl_xor(ssum, 16);
        ssum += __shfl_xor(ssum, 32);
        float inv = 1.f / ssum;
#pragma unroll
        for (int jt = 0; jt < 4; ++jt) {
            half4 h4, l4;
#pragma unroll
            for (int r = 0; r < 4; ++r) {
                float pv = sv[jt][r] * inv;
                half_t hh = (half_t)pv;
                h4[r] = hh;
                l4[r] = (half_t)(pv - (float)hh);
            }
            *(half4*)&Pbuf[0][w][l15 * 72 + jt * 16 + lq * 4] = h4;
            *(half4*)&Pbuf[1][w][l15 * 72 + jt * 16 + lq * 4] = l4;
        }
    }

    f32x4 vac[4][2];
#pragma unroll
    for (int mt = 0; mt < 4; ++mt)
#pragma unroll
        for (int nt = 0; nt < 2; ++nt) vac[mt][nt] = (f32x4){0.f, 0.f, 0.f, 0.f};
    __builtin_amdgcn_s_setprio(1);
#pragma unroll 2
    for (int kt = 0; kt < 8; ++kt) {
        int kc = kt * 32 + lq * 8;
        half8 ah[4], al[4], gh[2], gl[2];
#pragma unroll
        for (int mt = 0; mt < 4; ++mt) {
            int ro = (mt * 16 + l15) * 264 + kc;
            ah[mt] = *(const half8*)&Zh[ro];
            al[mt] = *(const half8*)&Zl[ro];
        }
#pragma unroll
        for (int nt = 0; nt < 2; ++nt) {
            size_t go = (size_t)(w * 32 + nt * 16 + l15) * 256 + kc;
            gh[nt] = *(const half8*)(WvTh + go);
            gl[nt] = *(const half8*)(WvTl + go);
        }
#pragma unroll
        for (int mt = 0; mt < 4; ++mt)
#pragma unroll
            for (int nt = 0; nt < 2; ++nt) {
                vac[mt][nt] = __builtin_amdgcn_mfma_f32_16x16x32_f16(ah[mt], gh[nt], vac[mt][nt], 0, 0, 0);
                vac[mt][nt] = __builtin_amdgcn_mfma_f32_16x16x32_f16(ah[mt], gl[nt], vac[mt][nt], 0, 0, 0);
                vac[mt][nt] = __builtin_amdgcn_mfma_f32_16x16x32_f16(al[mt], gh[nt], vac[mt][nt], 0, 0, 0);
            }
    }
    __builtin_amdgcn_s_setprio(0);
    __syncthreads();   // sync 3: S done reading T

    // VT write
#pragma unroll
    for (int mt = 0; mt < 4; ++mt)
#pragma unroll
        for (int nt = 0; nt < 2; ++nt) {
            int n = w * 32 + nt * 16 + l15;
            int m0 = mt * 16 + lq * 4;
            half4 h4, l4;
#pragma unroll
            for (int r = 0; r < 4; ++r) {
                float v = vac[mt][nt][r];
                half_t h = (half_t)v;
                h4[r] = h; l4[r] = (half_t)(v - (float)h);
            }
            *(half4*)&Ubuf[0][n * 72 + m0] = h4;
            *(half4*)&Ubuf[1][n * 72 + m0] = l4;
        }
    __syncthreads();   // sync 4: VT + P visible

    // ---- phase O
    f32x4 oc[4][2];
#pragma unroll
    for (int mt = 0; mt < 4; ++mt)
#pragma unroll
        for (int nt = 0; nt < 2; ++nt) oc[mt][nt] = (f32x4){0.f, 0.f, 0.f, 0.f};
    __builtin_amdgcn_s_setprio(1);
#pragma unroll
    for (int kt = 0; kt < 2; ++kt) {
        half8 pah[4], pal[4];
#pragma unroll
        for (int mt = 0; mt < 4; ++mt) {
            int po = l15 * 72 + kt * 32 + lq * 8;
            pah[mt] = *(const half8*)&Pbuf[0][mt][po];
            pal[mt] = *(const half8*)&Pbuf[1][mt][po];
        }
#pragma unroll
        for (int nt = 0; nt < 2; ++nt) {
            int n = w * 32 + nt * 16 + l15;
            half8 vbh = *(const half8*)&Ubuf[0][n * 72 + kt * 32 + lq * 8];
            half8 vbl = *(const half8*)&Ubuf[1][n * 72 + kt * 32 + lq * 8];
#pragma unroll
            for (int mt = 0; mt < 4; ++mt) {
                oc[mt][nt] = __builtin_amdgcn_mfma_f32_16x16x32_f16(pah[mt], vbh, oc[mt][nt], 0, 0, 0);
                oc[mt][nt] = __builtin_amdgcn_mfma_f32_16x16x32_f16(pah[mt], vbl, oc[mt][nt], 0, 0, 0);
                oc[mt][nt] = __builtin_amdgcn_mfma_f32_16x16x32_f16(pal[mt], vbh, oc[mt][nt], 0, 0, 0);
            }
        }
    }
    __builtin_amdgcn_s_setprio(0);

    // ---- epilogue: z_out = O + 0.1*x0; zf1 col-means for this wave's band
    float zfs[2] = {0.f, 0.f};
#pragma unroll
    for (int mt = 0; mt < 4; ++mt)
#pragma unroll
        for (int nt = 0; nt < 2; ++nt)
#pragma unroll
            for (int r = 0; r < 4; ++r) {
                int i = mt * 16 + lq * 4 + r;
                int c = w * 32 + nt * 16 + l15;
                int zo = i * 264 + c;
                float x0 = (float)Zh[zo] + (float)Zl[zo];
                float z1 = oc[mt][nt][r] + 0.1f * x0;
                zb[(size_t)i * FF + c] = z1;
                zfs[nt] += z1;
            }
#pragma unroll
    for (int nt = 0; nt < 2; ++nt) {
        zfs[nt] += __shfl_xor(zfs[nt], 16);
        zfs[nt] += __shfl_xor(zfs[nt], 32);
    }
    if (lq == 0) {
#pragma unroll
        for (int nt = 0; nt < 2; ++nt)
            zf1g[b * FF + w * 32 + nt * 16 + l15] = zfs[nt] * (1.f / 64.f);
    }
}

// ---------------------------------------------------------------------------
// Split-fp16 MFMA GEMM: C[M][768] = A[M][256] @ W[256][768].  Used for zfW.
__global__ __launch_bounds__(256) void gemm_split(const float* __restrict__ A,
                                                  const half_t* __restrict__ WTh,
                                                  const half_t* __restrict__ WTl,
                                                  float* __restrict__ C) {
    __shared__ float As[128][36];
    int bm = blockIdx.x / 6;
    int bn = blockIdx.x % 6;
    int tid = threadIdx.x;
    int w = tid >> 6;
    int lane = tid & 63;
    int wr = w >> 1, wc = w & 1;
    int l15 = lane & 15;
    int lq  = lane >> 4;

    f32x4 acc[4][4];
#pragma unroll
    for (int i = 0; i < 4; ++i)
#pragma unroll
        for (int j = 0; j < 4; ++j) acc[i][j] = (f32x4){0.f, 0.f, 0.f, 0.f};

    const float* Ablk = A + (size_t)bm * 128 * 256;
    int colbase = bn * 128 + wc * 64;

    int srow = tid >> 1;
    int sseg = (tid & 1) * 16;

    for (int k0 = 0; k0 < 256; k0 += 32) {
        __syncthreads();
        {
            const float* src = Ablk + (size_t)srow * 256 + k0 + sseg;
            f32x4 v0 = *(const f32x4*)(src);
            f32x4 v1 = *(const f32x4*)(src + 4);
            f32x4 v2 = *(const f32x4*)(src + 8);
            f32x4 v3 = *(const f32x4*)(src + 12);
            *(f32x4*)&As[srow][sseg]      = v0;
            *(f32x4*)&As[srow][sseg + 4]  = v1;
            *(f32x4*)&As[srow][sseg + 8]  = v2;
            *(f32x4*)&As[srow][sseg + 12] = v3;
        }
        __syncthreads();

        half8 bh[4], bl[4];
#pragma unroll
        for (int tj = 0; tj < 4; ++tj) {
            size_t off = (size_t)(colbase + tj * 16 + l15) * 256 + k0 + lq * 8;
            bh[tj] = *(const half8*)(WTh + off);
            bl[tj] = *(const half8*)(WTl + off);
        }

        half8 ah[4], al[4];
#pragma unroll
        for (int ti = 0; ti < 4; ++ti) {
            const float* ap = &As[wr * 64 + ti * 16 + l15][lq * 8];
            f32x4 a0 = *(const f32x4*)(ap);
            f32x4 a1 = *(const f32x4*)(ap + 4);
#pragma unroll
            for (int j = 0; j < 4; ++j) {
                float x = a0[j];
                half_t h = (half_t)x;
                ah[ti][j] = h;
                al[ti][j] = (half_t)(x - (float)h);
            }
#pragma unroll
            for (int j = 0; j < 4; ++j) {
                float x = a1[j];
                half_t h = (half_t)x;
                ah[ti][4 + j] = h;
                al[ti][4 + j] = (half_t)(x - (float)h);
            }
        }

#pragma unroll
        for (int ti = 0; ti < 4; ++ti)
#pragma unroll
            for (int tj = 0; tj < 4; ++tj)
                acc[ti][tj] = __builtin_amdgcn_mfma_f32_16x16x32_f16(ah[ti], bh[tj], acc[ti][tj], 0, 0, 0);
#pragma unroll
        for (int ti = 0; ti < 4; ++ti)
#pragma unroll
            for (int tj = 0; tj < 4; ++tj)
                acc[ti][tj] = __builtin_amdgcn_mfma_f32_16x16x32_f16(ah[ti], bl[tj], acc[ti][tj], 0, 0, 0);
#pragma unroll
        for (int ti = 0; ti < 4; ++ti)
#pragma unroll
            for (int tj = 0; tj < 4; ++tj)
                acc[ti][tj] = __builtin_amdgcn_mfma_f32_16x16x32_f16(al[ti], bh[tj], acc[ti][tj], 0, 0, 0);
    }

    float* Cb = C + (size_t)(bm * 128 + wr * 64) * 768 + bn * 128 + wc * 64;
#pragma unroll
    for (int ti = 0; ti < 4; ++ti)
#pragma unroll
        for (int tj = 0; tj < 4; ++tj) {
            int r0 = ti * 16 + lq * 4;
            int c0 = tj * 16 + l15;
#pragma unroll
            for (int r = 0; r < 4; ++r)
                Cb[(size_t)(r0 + r) * 768 + c0] = acc[ti][tj][r];
        }
}

// ---------------------------------------------------------------------------
// Stack step + mag (unchanged from R10, incl. stride-780 Q).
__global__ __launch_bounds__(256, 2) void k_stack2(
        const float* __restrict__ zf1,
        const float* __restrict__ ctrl_w, const float* __restrict__ ctrl_b,
        float* __restrict__ ptrv, float* __restrict__ qbuf,
        const float* __restrict__ zfW,
        float* __restrict__ readv, float* __restrict__ zf2,
        const float* __restrict__ halt_w, const float* __restrict__ halt_b,
        float* __restrict__ pval,
        const float* __restrict__ z, float* __restrict__ magpart) {
    __shared__ float zf[256];
    __shared__ float g[3];
    __shared__ float oldp[16], np[16];
    __shared__ float Q[16][780];
    __shared__ float sm[16][17];
    __shared__ float rowmax[16], rowsum[16], pw[16];
    __shared__ float rd[256];
    __shared__ float red[256];

    int b = blockIdx.x, tid = threadIdx.x;
    int w = tid >> 6, lane = tid & 63;

    zf[tid] = zf1[b * FF + tid];
    if (tid < 16) oldp[tid] = ptrv[b * STK + tid];
    __syncthreads();
    if (w < 3) {
        float s = 0.f;
#pragma unroll
        for (int q = 0; q < 4; ++q) {
            int c = lane + 64 * q;
            s += zf[c] * ctrl_w[c * 3 + w];
        }
#pragma unroll
        for (int off = 1; off < 64; off <<= 1) s += __shfl_xor(s, off);
        if (lane == 0) g[w] = 1.f / (1.f + expf(-(s + ctrl_b[w])));
    }
    __syncthreads();
    float tot = g[0] + g[1] + g[2] + 1e-6f;
    float push = g[0] / tot, pop = g[1] / tot, stay = g[2] / tot;
    if (tid < 16) {
        float v = push * oldp[(tid + 15) & 15] + pop * oldp[(tid + 1) & 15] + stay * oldp[tid];
        np[tid] = v;
        ptrv[b * STK + tid] = v;
    }

    float omp = 1.f - push;
    float zw0 = push * zfW[b * 768 + tid];
    float zw1 = push * zfW[b * 768 + 256 + tid];
    float zw2 = push * zfW[b * 768 + 512 + tid];
    float* qb = qbuf + (size_t)b * (STK * 768);
#pragma unroll 4
    for (int t16 = 0; t16 < 16; ++t16) {
        float q0 = qb[t16 * 768 + tid]       * omp + zw0;
        float q1 = qb[t16 * 768 + 256 + tid] * omp + zw1;
        float q2 = qb[t16 * 768 + 512 + tid] * omp + zw2;
        qb[t16 * 768 + tid]       = q0;
        qb[t16 * 768 + 256 + tid] = q1;
        qb[t16 * 768 + 512 + tid] = q2;
        Q[t16][tid] = q0;
        Q[t16][256 + tid] = q1;
        Q[t16][512 + tid] = q2;
    }
    __syncthreads();

    {
        int i = tid >> 4, j = tid & 15;
        float s = 0.f;
#pragma unroll 4
        for (int c = 0; c < 256; c += 4) {
            f32x4 qi = *(const f32x4*)&Q[i][c];
            f32x4 kj = *(const f32x4*)&Q[j][256 + c];
            s += qi[0] * kj[0] + qi[1] * kj[1] + qi[2] * kj[2] + qi[3] * kj[3];
        }
        s *= 0.08838834764831845f;
        sm[i][j] = s;
        __syncthreads();
        if (tid < 16) {
            float m = -1e30f;
            for (int jj = 0; jj < 16; ++jj) m = fmaxf(m, sm[tid][jj]);
            float su = 0.f;
            for (int jj = 0; jj < 16; ++jj) su += expf(sm[tid][jj] - m);
            rowmax[tid] = m; rowsum[tid] = su;
        }
        __syncthreads();
        float p = expf(s - rowmax[i]) / rowsum[i];
        sm[i][j] = p;
        __syncthreads();
        if (tid < 16) {
            float a = 0.f;
            for (int s2 = 0; s2 < 16; ++s2) a += np[s2] * sm[s2][tid];
            pw[tid] = a;
        }
        __syncthreads();
    }

    {
        float a = 0.f;
#pragma unroll
        for (int jj = 0; jj < 16; ++jj) a += pw[jj] * Q[jj][512 + tid];
        rd[tid] = a;
        readv[b * FF + tid] = a;
        float z2 = zf[tid] + 0.1f * a;
        zf2[b * FF + tid] = z2;
        red[tid] = z2 * halt_w[tid];
        __syncthreads();
        for (int off = 128; off > 0; off >>= 1) {
            if (tid < off) red[tid] += red[tid + off];
            __syncthreads();
        }
        if (tid == 0) pval[b] = 1.f / (1.f + expf(-(red[0] + halt_b[0])));
        __syncthreads();
    }

    {
        int d = tid & 127, hf = tid >> 7;
        float rr = 0.1f * rd[d];
        float ri = 0.1f * rd[DD + d];
        const float* zb = z + (size_t)b * (SS * FF);
        float ms = 0.f, msq = 0.f;
        for (int s32 = 0; s32 < 32; ++s32) {
            int s = hf * 32 + s32;
            float zr = zb[s * FF + d] + rr;
            float zi = zb[s * FF + DD + d] + ri;
            float m2 = zr * zr + zi * zi;
            ms += sqrtf(m2); msq += m2;
        }
        red[tid] = ms;
        __syncthreads();
        for (int off = 128; off > 0; off >>= 1) {
            if (tid < off) red[tid] += red[tid + off];
            __syncthreads();
        }
        float tms = red[0];
        __syncthreads();
        red[tid] = msq;
        __syncthreads();
        for (int off = 128; off > 0; off >>= 1) {
            if (tid < off) red[tid] += red[tid + off];
            __syncthreads();
        }
        if (tid == 0) { magpart[2 * b] = tms; magpart[2 * b + 1] = red[0]; }
    }
}

// ---------------------------------------------------------------------------
// Lean VQ kernel: 256 threads/block, wave-shuffle reductions (~5 barriers).
// Writes delta = read + quant, wact, halt, probs.
__global__ __launch_bounds__(256) void k_vq2(
        const float* __restrict__ zf2g, const float* __restrict__ readv,
        float* __restrict__ probs, float* __restrict__ halt,
        const float* __restrict__ pvalg, const float* __restrict__ magp,
        const float* __restrict__ cb, const float* __restrict__ cb2,
        const float* __restrict__ adj,
        float* __restrict__ delta, float* __restrict__ wact, int t) {
    __shared__ float zf[256];
    __shared__ float pr[128];
    __shared__ float upred[8];
    __shared__ float zzred[4];
    __shared__ float mxred[4];
    __shared__ float sered[4];

    int b = blockIdx.x, tid = threadIdx.x;
    int w = tid >> 6, lane = tid & 63;

    zf[tid] = zf2g[b * FF + tid];

    // up (global var from magp) — 2-barrier wave reduction
    float up = 0.f;
    if (t > 0) {
        f32x4 mv = *(const f32x4*)(magp + tid * 4);   // 2 ms (even) + 2 msq (odd)
        float pa = mv[0] + mv[2];
        float pb = mv[1] + mv[3];
#pragma unroll
        for (int off = 1; off < 64; off <<= 1) {
            pa += __shfl_xor(pa, off);
            pb += __shfl_xor(pb, off);
        }
        if (lane == 0) { upred[w * 2] = pa; upred[w * 2 + 1] = pb; }
    }
    __syncthreads();   // zf visible; upred ready
    if (t > 0) {
        float tms  = upred[0] + upred[2] + upred[4] + upred[6];
        float tmsq = upred[1] + upred[3] + upred[5] + upred[7];
        const float N = 4194304.f;   // B*S*D
        float mean = tms / N;
        float var = tmsq / N - mean * mean;
        float x = var / (1.f + 1e-6f);
        up = (x > 20.f) ? x : log1pf(expf(x));
    }

    // zz = ||zf2||^2 — wave reduce
    {
        float part = zf[tid] * zf[tid];
#pragma unroll
        for (int off = 1; off < 64; off <<= 1) part += __shfl_xor(part, off);
        if (lane == 0) zzred[w] = part;
    }
    __syncthreads();
    float zz = zzred[0] + zzred[1] + zzred[2] + zzred[3];

    // dist + gb: n = tid>>1, half = tid&1 (128-elem halves), pair-combined
    int n = tid >> 1, half = tid & 1;
    float dacc = 0.f;
    {
        const float* cbn = cb + n * FF + half * 128;
        const float* zfp = zf + half * 128;
#pragma unroll 8
        for (int c2 = 0; c2 < 128; c2 += 4) {
            f32x4 cv = *(const f32x4*)(cbn + c2);
            dacc += cv[0] * zfp[c2] + cv[1] * zfp[c2 + 1] + cv[2] * zfp[c2 + 2] + cv[3] * zfp[c2 + 3];
        }
        dacc += __shfl_xor(dacc, 1);
    }
    float gacc = 0.f;
    if (t > 0) {
        const float* pp = probs + b * NSYM;
        for (int k = half * 64; k < half * 64 + 64; ++k)
            gacc += pp[k] * adj[k * NSYM + n];
        gacc += __shfl_xor(gacc, 1);
    }

    float dist = (zz + cb2[n] - 2.f * dacc) * (1.f / 256.f);
    float dtot = dist;
    if (t > 0) dtot = dist - 0.01f * up * (1.f / (1.f + expf(-gacc)));
    float vval = -dtot;   // TEMP = 1

    // max over n (values duplicated per pair — max unaffected)
    {
        float m = vval;
#pragma unroll
        for (int off = 1; off < 64; off <<= 1) m = fmaxf(m, __shfl_xor(m, off));
        if (lane == 0) mxred[w] = m;
    }
    __syncthreads();
    float mx = fmaxf(fmaxf(mxred[0], mxred[1]), fmaxf(mxred[2], mxred[3]));

    float e = expf(vval - mx);
    {
        float s = (half == 0) ? e : 0.f;   // count each n once
#pragma unroll
        for (int off = 1; off < 64; off <<= 1) s += __shfl_xor(s, off);
        if (lane == 0) sered[w] = s;
    }
    __syncthreads();
    float se = sered[0] + sered[1] + sered[2] + sered[3];
    float psm = e / se;
    if (half == 0) {
        pr[n] = psm;
        probs[b * NSYM + n] = psm;
    }
    __syncthreads();

    // quant: c = tid; q = sum_k pr[k]*cb[k][c] (coalesced rows)
    float q = 0.f;
#pragma unroll 4
    for (int k = 0; k < NSYM; ++k) q += pr[k] * cb[k * FF + tid];
    delta[b * FF + tid] = readv[b * FF + tid] + q;

    if (tid == 0) {
        float h = halt[b], p = pvalg[b];
        float running = (h < 0.99f) ? 1.f : 0.f;
        float w2 = (((h + p * running) >= 0.99f) ? (1.f - h) : p) * running;
        halt[b] = h + w2;
        wact[b] = w2;
    }
}

// ---------------------------------------------------------------------------
// Final deferred delta + ACT accumulation.
__global__ __launch_bounds__(256) void k_epilogue(const float* __restrict__ z,
                                                  const float* __restrict__ delta,
                                                  const float* __restrict__ wact,
                                                  float* __restrict__ acc) {
    int idx = blockIdx.x * 256 + threadIdx.x;   // grid 32768 -> 8388608
    int b = idx >> 14;
    int c = idx & 255;
    float wa = wact[b];
    if (wa != 0.0f)
        acc[idx] += wa * (z[idx] + 0.1f * delta[b * FF + c]);
}

// ---------------------------------------------------------------------------
extern "C" void kernel_launch(void* const* d_in, const int* in_sizes, int n_in,
                              void* d_out, int out_size, void* d_ws, size_t ws_size,
                              hipStream_t stream) {
    const float* z_real  = (const float*)d_in[0];
    const float* z_imag  = (const float*)d_in[1];
    const float* attn_wr = (const float*)d_in[2];
    const float* attn_wi = (const float*)d_in[3];
    const float* mem_wr  = (const float*)d_in[4];
    const float* mem_wi  = (const float*)d_in[5];
    const float* ctrl_w  = (const float*)d_in[6];
    const float* ctrl_b  = (const float*)d_in[7];
    const float* halt_w  = (const float*)d_in[8];
    const float* halt_b  = (const float*)d_in[9];
    const float* codebook  = (const float*)d_in[10];
    const float* adjacency = (const float*)d_in[11];

    float* ws = (float*)d_ws;
    float* z      = ws + Z_OFF;
    float* WT32   = ws + QKV_OFF;
    half_t* GTh   = (half_t*)(ws + QKV_OFF + 196608);
    half_t* GTl   = GTh + 65536;
    half_t* WvTh  = GTl + 65536;
    half_t* WvTl  = WvTh + 65536;
    float* zfW    = ws + ZFW_OFF;
    float* qbuf   = ws + QBUF_OFF;
    float* ptrv   = ws + PTR_OFF;
    float* zf1    = ws + ZF1_OFF;
    float* zf2    = ws + ZF2_OFF;
    float* readv  = ws + READ_OFF;
    float* probs  = ws + PROBS_OFF;
    float* delta  = ws + DELTA_OFF;
    float* halt   = ws + HALT_OFF;
    float* pval   = ws + PVAL_OFF;
    float* wact   = ws + WACT_OFF;
    float* magp   = ws + MAGP_OFF;
    half_t* MTh   = (half_t*)(ws + MQKV_OFF);
    half_t* MTl   = (half_t*)(ws + MQKV_OFF) + 196608;
    float* cb2    = ws + CB2_OFF;
    float* acc    = (float*)d_out;

    k_buildwt32<<<768, 256, 0, stream>>>(attn_wr, attn_wi, WT32);
    k_buildG<<<256, 256, 0, stream>>>(WT32, GTh, GTl);
    k_splitWv<<<256, 256, 0, stream>>>(WT32, WvTh, WvTl);
    k_buildwt<<<768, 256, 0, stream>>>(mem_wr, mem_wi, MTh, MTl);
    k_cb2<<<1, 128, 0, stream>>>(codebook, cb2);
    k_init<<<32768, 256, 0, stream>>>(z_real, z_imag, z, qbuf, ptrv, halt, acc,
                                      delta, wact);

    for (int t = 0; t < NDEPTH; ++t) {
        k_attn8<<<BB, 512, 0, stream>>>(z, GTh, GTl, WvTh, WvTl, delta, wact, acc, zf1);
        gemm_split<<<(BB / 128) * 6, 256, 0, stream>>>(zf1, MTh, MTl, zfW);   // 24 blocks
        k_stack2<<<BB, 256, 0, stream>>>(zf1, ctrl_w, ctrl_b, ptrv, qbuf, zfW,
                                         readv, zf2, halt_w, halt_b, pval, z, magp);
        k_vq2<<<BB, 256, 0, stream>>>(zf2, readv, probs, halt, pval, magp,
                                      codebook, cb2, adjacency, delta, wact, t);
    }
    k_epilogue<<<32768, 256, 0, stream>>>(z, delta, wact, acc);
}

// Round 12
// 838.047 us; speedup vs baseline: 4.7905x; 1.0949x over previous
//
#include <hip/hip_runtime.h>
#include <math.h>

// Problem constants
#define BB 512
#define SS 64
#define DD 128
#define FF 256   // 2D
#define NSYM 128
#define STK 16
#define NDEPTH 8

typedef _Float16 half_t;
typedef __attribute__((ext_vector_type(4))) _Float16 half4;
typedef __attribute__((ext_vector_type(8))) _Float16 half8;
typedef __attribute__((ext_vector_type(4))) float f32x4;

// Workspace offsets (in floats)
#define Z_OFF      0ull                    // B*S*F      = 8388608
#define QKV_OFF    8388608ull              // WT32 + GT/WvT split planes (attn)
#define ZFW_OFF    33554432ull             // zfWv (131072) + MvTh/MvTl (65536)
#define MV_OFF     35651584ull             // mv state B*256 = 131072
#define SIG_OFF    35782656ull             // sigma B = 512
#define ZF1_OFF    41951232ull             // B*256      = 131072
#define ZF2_OFF    42082304ull             // B*256      = 131072
#define READ_OFF   42213376ull             // B*256      = 131072
#define PROBS_OFF  42344448ull             // B*128      = 65536
#define DELTA_OFF  42409984ull             // B*256      = 131072 (read + quant)
#define HALT_OFF   42541056ull             // B          = 512
#define PVAL_OFF   42541568ull             // B          = 512
#define WACT_OFF   42542080ull             // B          = 512
#define MAGP_OFF   42542592ull             // B*2        = 1024
#define MQKV_OFF   42740224ull             // MT32 fp32 (mem combined) = 196608
#define CB2_OFF    42936832ull             // 128

// ---------------------------------------------------------------------------
// Combined transposed weight, fp32: WT32[col=h*256+c][e] = W_h[e][c]
__global__ void k_buildwt32(const float* __restrict__ wr, const float* __restrict__ wi,
                            float* __restrict__ WT32) {
    int idx = blockIdx.x * 256 + threadIdx.x;   // 196608 total, grid=768
    if (idx >= 768 * 256) return;
    int col = idx >> 8;
    int e   = idx & 255;
    int h   = col >> 8;
    int c   = col & 255;
    const float* Wr = wr + h * DD * DD;
    const float* Wi = wi + h * DD * DD;
    float v;
    if (c < DD) {
        v = (e < DD) ? Wr[c * DD + e] : -Wi[c * DD + (e - DD)];
    } else {
        int j = c - DD;
        v = (e < DD) ? Wi[j * DD + e] : Wr[j * DD + (e - DD)];
    }
    WT32[idx] = v;
}

// GT[n][e] = G[e][n] = sum_c Wq[e][c]*Wk[n][c], split to fp16 h/l (unscaled).
__global__ __launch_bounds__(256) void k_buildG(const float* __restrict__ WT32,
                                                half_t* __restrict__ GTh,
                                                half_t* __restrict__ GTl) {
    __shared__ float kcol[256];
    int n = blockIdx.x;
    int e = threadIdx.x;
    kcol[e] = WT32[65536 + e * 256 + n];   // Wk[n][c=e]
    __syncthreads();
    float s = 0.f;
    for (int c = 0; c < 256; ++c) s += kcol[c] * WT32[c * 256 + e];  // Wq[e][c]
    half_t h = (half_t)s;
    GTh[n * 256 + e] = h;
    GTl[n * 256 + e] = (half_t)(s - (float)h);
}

// Split the V-head columns (cols 512..767 of a combined WT32) to fp16 h/l.
__global__ void k_splitWv(const float* __restrict__ WT32,
                          half_t* __restrict__ WvTh, half_t* __restrict__ WvTl) {
    int idx = blockIdx.x * 256 + threadIdx.x;   // 65536, grid 256
    float v = WT32[131072 + idx];   // WvT[n][e]
    half_t h = (half_t)v;
    WvTh[idx] = h;
    WvTl[idx] = (half_t)(v - (float)h);
}

__global__ void k_cb2(const float* __restrict__ cb, float* __restrict__ cb2) {
    int n = threadIdx.x;   // 128 threads
    float s = 0.f;
    for (int c = 0; c < FF; ++c) { float v = cb[n * FF + c]; s += v * v; }
    cb2[n] = s;
}

__global__ __launch_bounds__(256) void k_init(const float* __restrict__ zr_in,
                                              const float* __restrict__ zi_in,
                                              float* __restrict__ z, float* __restrict__ mv,
                                              float* __restrict__ sigma,
                                              float* __restrict__ halt, float* __restrict__ acc,
                                              float* __restrict__ delta, float* __restrict__ wact) {
    size_t idx = (size_t)blockIdx.x * 256 + threadIdx.x;  // grid 32768 -> 8388608
    int c = (int)(idx & 255);
    size_t bs = idx >> 8;
    z[idx] = (c < DD) ? zr_in[bs * DD + c] : zi_in[bs * DD + (c - DD)];
    acc[idx] = 0.f;
    if (idx < 131072) { mv[idx] = 0.f; delta[idx] = 0.f; }
    if (idx < 512)   { halt[idx] = 0.f; wact[idx] = 0.f; sigma[idx] = 1.f; }
}

// ---------------------------------------------------------------------------
// Fused attention step (lean R8 body + setprio + kt unroll). 8 waves, 1 blk/CU.
__global__ __launch_bounds__(512, 1) void k_attn8(
        float* __restrict__ z,
        const half_t* __restrict__ GTh, const half_t* __restrict__ GTl,
        const half_t* __restrict__ WvTh, const half_t* __restrict__ WvTl,
        const float* __restrict__ delta, const float* __restrict__ wact,
        float* __restrict__ acc, float* __restrict__ zf1g) {
    __shared__ half_t Zh[16896];         // 64 x 264, 33 KB
    __shared__ half_t Zl[16896];
    __shared__ half_t Ubuf[2][18432];    // union: T[64][264] / VT[256][72]
    __shared__ half_t Pbuf[2][4][1152];

    int b = blockIdx.x, tid = threadIdx.x;
    int w = tid >> 6, lane = tid & 63;
    int l15 = lane & 15, lq = lane >> 4;
    float* zb = z + (size_t)b * (SS * FF);
    float* accb = acc + (size_t)b * (SS * FF);

    // ---- phase 0: x0 = z + 0.1*delta; deferred acc; split to LDS
    float wa = wact[b];
    f32x4 dv = *(const f32x4*)(delta + b * FF + lane * 4);
    bool doacc = (wa != 0.0f);
#pragma unroll
    for (int it = 0; it < 8; ++it) {
        int i = w * 8 + it;
        f32x4 zv = *(const f32x4*)(zb + (size_t)i * FF + lane * 4);
        f32x4 x0;
#pragma unroll
        for (int jj = 0; jj < 4; ++jj) x0[jj] = zv[jj] + 0.1f * dv[jj];
        if (doacc) {
            f32x4 av = *(const f32x4*)(accb + (size_t)i * FF + lane * 4);
#pragma unroll
            for (int jj = 0; jj < 4; ++jj) av[jj] += wa * x0[jj];
            *(f32x4*)(accb + (size_t)i * FF + lane * 4) = av;
        }
        half4 h4, l4;
#pragma unroll
        for (int jj = 0; jj < 4; ++jj) {
            half_t h = (half_t)x0[jj];
            h4[jj] = h; l4[jj] = (half_t)(x0[jj] - (float)h);
        }
        *(half4*)&Zh[i * 264 + lane * 4] = h4;
        *(half4*)&Zl[i * 264 + lane * 4] = l4;
    }
    __syncthreads();   // sync 1: Z staged

    // ---- phase T: T = x0 @ G, wave w owns 32-col band.
    {
        f32x4 tac[4][2];
#pragma unroll
        for (int mt = 0; mt < 4; ++mt)
#pragma unroll
            for (int nt = 0; nt < 2; ++nt) tac[mt][nt] = (f32x4){0.f, 0.f, 0.f, 0.f};
        __builtin_amdgcn_s_setprio(1);
#pragma unroll 2
        for (int kt = 0; kt < 8; ++kt) {
            int kc = kt * 32 + lq * 8;
            half8 ah[4], al[4], gh[2], gl[2];
#pragma unroll
            for (int mt = 0; mt < 4; ++mt) {
                int ro = (mt * 16 + l15) * 264 + kc;
                ah[mt] = *(const half8*)&Zh[ro];
                al[mt] = *(const half8*)&Zl[ro];
            }
#pragma unroll
            for (int nt = 0; nt < 2; ++nt) {
                size_t go = (size_t)(w * 32 + nt * 16 + l15) * 256 + kc;
                gh[nt] = *(const half8*)(GTh + go);
                gl[nt] = *(const half8*)(GTl + go);
            }
#pragma unroll
            for (int mt = 0; mt < 4; ++mt)
#pragma unroll
                for (int nt = 0; nt < 2; ++nt) {
                    tac[mt][nt] = __builtin_amdgcn_mfma_f32_16x16x32_f16(ah[mt], gh[nt], tac[mt][nt], 0, 0, 0);
                    tac[mt][nt] = __builtin_amdgcn_mfma_f32_16x16x32_f16(ah[mt], gl[nt], tac[mt][nt], 0, 0, 0);
                    tac[mt][nt] = __builtin_amdgcn_mfma_f32_16x16x32_f16(al[mt], gh[nt], tac[mt][nt], 0, 0, 0);
                }
        }
        __builtin_amdgcn_s_setprio(0);
        const float scale = 0.08838834764831845f;
#pragma unroll
        for (int mt = 0; mt < 4; ++mt)
#pragma unroll
            for (int nt = 0; nt < 2; ++nt)
#pragma unroll
                for (int r = 0; r < 4; ++r) {
                    int m = mt * 16 + lq * 4 + r;
                    int n = w * 32 + nt * 16 + l15;
                    float v = tac[mt][nt][r] * scale;
                    half_t h = (half_t)v;
                    Ubuf[0][m * 264 + n] = h;
                    Ubuf[1][m * 264 + n] = (half_t)(v - (float)h);
                }
    }
    __syncthreads();   // sync 2: T ready

    // ---- phase B: waves 0-3: S/softmax/P; all waves: V band.
    if (w < 4) {
        f32x4 sac[4];
#pragma unroll
        for (int jt = 0; jt < 4; ++jt) sac[jt] = (f32x4){0.f, 0.f, 0.f, 0.f};
        __builtin_amdgcn_s_setprio(1);
#pragma unroll 2
        for (int kt = 0; kt < 8; ++kt) {
            int kc = kt * 32 + lq * 8;
            int to = (w * 16 + l15) * 264 + kc;
            half8 bh = *(const half8*)&Ubuf[0][to];
            half8 bl = *(const half8*)&Ubuf[1][to];
            half8 ah[4], al[4];
#pragma unroll
            for (int jt = 0; jt < 4; ++jt) {
                int ro = (jt * 16 + l15) * 264 + kc;
                ah[jt] = *(const half8*)&Zh[ro];
                al[jt] = *(const half8*)&Zl[ro];
            }
#pragma unroll
            for (int jt = 0; jt < 4; ++jt) {
                sac[jt] = __builtin_amdgcn_mfma_f32_16x16x32_f16(ah[jt], bh, sac[jt], 0, 0, 0);
                sac[jt] = __builtin_amdgcn_mfma_f32_16x16x32_f16(ah[jt], bl, sac[jt], 0, 0, 0);
                sac[jt] = __builtin_amdgcn_mfma_f32_16x16x32_f16(al[jt], bh, sac[jt], 0, 0, 0);
            }
        }
        __builtin_amdgcn_s_setprio(0);
        float sv[4][4];
        float mx = -1e30f;
#pragma unroll
        for (int jt = 0; jt < 4; ++jt)
#pragma unroll
            for (int r = 0; r < 4; ++r) { sv[jt][r] = sac[jt][r]; mx = fmaxf(mx, sv[jt][r]); }
        mx = fmaxf(mx, __shfl_xor(mx, 16));
        mx = fmaxf(mx, __shfl_xor(mx, 32));
        float ssum = 0.f;
#pragma unroll
        for (int jt = 0; jt < 4; ++jt)
#pragma unroll
            for (int r = 0; r < 4; ++r) { float e = expf(sv[jt][r] - mx); sv[jt][r] = e; ssum += e; }
        ssum += __shfl_xor(ssum, 16);
        ssum += __shfl_xor(ssum, 32);
        float inv = 1.f / ssum;
#pragma unroll
        for (int jt = 0; jt < 4; ++jt) {
            half4 h4, l4;
#pragma unroll
            for (int r = 0; r < 4; ++r) {
                float pv = sv[jt][r] * inv;
                half_t hh = (half_t)pv;
                h4[r] = hh;
                l4[r] = (half_t)(pv - (float)hh);
            }
            *(half4*)&Pbuf[0][w][l15 * 72 + jt * 16 + lq * 4] = h4;
            *(half4*)&Pbuf[1][w][l15 * 72 + jt * 16 + lq * 4] = l4;
        }
    }

    f32x4 vac[4][2];
#pragma unroll
    for (int mt = 0; mt < 4; ++mt)
#pragma unroll
        for (int nt = 0; nt < 2; ++nt) vac[mt][nt] = (f32x4){0.f, 0.f, 0.f, 0.f};
    __builtin_amdgcn_s_setprio(1);
#pragma unroll 2
    for (int kt = 0; kt < 8; ++kt) {
        int kc = kt * 32 + lq * 8;
        half8 ah[4], al[4], gh[2], gl[2];
#pragma unroll
        for (int mt = 0; mt < 4; ++mt) {
            int ro = (mt * 16 + l15) * 264 + kc;
            ah[mt] = *(const half8*)&Zh[ro];
            al[mt] = *(const half8*)&Zl[ro];
        }
#pragma unroll
        for (int nt = 0; nt < 2; ++nt) {
            size_t go = (size_t)(w * 32 + nt * 16 + l15) * 256 + kc;
            gh[nt] = *(const half8*)(WvTh + go);
            gl[nt] = *(const half8*)(WvTl + go);
        }
#pragma unroll
        for (int mt = 0; mt < 4; ++mt)
#pragma unroll
            for (int nt = 0; nt < 2; ++nt) {
                vac[mt][nt] = __builtin_amdgcn_mfma_f32_16x16x32_f16(ah[mt], gh[nt], vac[mt][nt], 0, 0, 0);
                vac[mt][nt] = __builtin_amdgcn_mfma_f32_16x16x32_f16(ah[mt], gl[nt], vac[mt][nt], 0, 0, 0);
                vac[mt][nt] = __builtin_amdgcn_mfma_f32_16x16x32_f16(al[mt], gh[nt], vac[mt][nt], 0, 0, 0);
            }
    }
    __builtin_amdgcn_s_setprio(0);
    __syncthreads();   // sync 3: S done reading T

    // VT write
#pragma unroll
    for (int mt = 0; mt < 4; ++mt)
#pragma unroll
        for (int nt = 0; nt < 2; ++nt) {
            int n = w * 32 + nt * 16 + l15;
            int m0 = mt * 16 + lq * 4;
            half4 h4, l4;
#pragma unroll
            for (int r = 0; r < 4; ++r) {
                float v = vac[mt][nt][r];
                half_t h = (half_t)v;
                h4[r] = h; l4[r] = (half_t)(v - (float)h);
            }
            *(half4*)&Ubuf[0][n * 72 + m0] = h4;
            *(half4*)&Ubuf[1][n * 72 + m0] = l4;
        }
    __syncthreads();   // sync 4: VT + P visible

    // ---- phase O
    f32x4 oc[4][2];
#pragma unroll
    for (int mt = 0; mt < 4; ++mt)
#pragma unroll
        for (int nt = 0; nt < 2; ++nt) oc[mt][nt] = (f32x4){0.f, 0.f, 0.f, 0.f};
    __builtin_amdgcn_s_setprio(1);
#pragma unroll
    for (int kt = 0; kt < 2; ++kt) {
        half8 pah[4], pal[4];
#pragma unroll
        for (int mt = 0; mt < 4; ++mt) {
            int po = l15 * 72 + kt * 32 + lq * 8;
            pah[mt] = *(const half8*)&Pbuf[0][mt][po];
            pal[mt] = *(const half8*)&Pbuf[1][mt][po];
        }
#pragma unroll
        for (int nt = 0; nt < 2; ++nt) {
            int n = w * 32 + nt * 16 + l15;
            half8 vbh = *(const half8*)&Ubuf[0][n * 72 + kt * 32 + lq * 8];
            half8 vbl = *(const half8*)&Ubuf[1][n * 72 + kt * 32 + lq * 8];
#pragma unroll
            for (int mt = 0; mt < 4; ++mt) {
                oc[mt][nt] = __builtin_amdgcn_mfma_f32_16x16x32_f16(pah[mt], vbh, oc[mt][nt], 0, 0, 0);
                oc[mt][nt] = __builtin_amdgcn_mfma_f32_16x16x32_f16(pah[mt], vbl, oc[mt][nt], 0, 0, 0);
                oc[mt][nt] = __builtin_amdgcn_mfma_f32_16x16x32_f16(pal[mt], vbh, oc[mt][nt], 0, 0, 0);
            }
        }
    }
    __builtin_amdgcn_s_setprio(0);

    // ---- epilogue: z_out = O + 0.1*x0; zf1 col-means for this wave's band
    float zfs[2] = {0.f, 0.f};
#pragma unroll
    for (int mt = 0; mt < 4; ++mt)
#pragma unroll
        for (int nt = 0; nt < 2; ++nt)
#pragma unroll
            for (int r = 0; r < 4; ++r) {
                int i = mt * 16 + lq * 4 + r;
                int c = w * 32 + nt * 16 + l15;
                int zo = i * 264 + c;
                float x0 = (float)Zh[zo] + (float)Zl[zo];
                float z1 = oc[mt][nt][r] + 0.1f * x0;
                zb[(size_t)i * FF + c] = z1;
                zfs[nt] += z1;
            }
#pragma unroll
    for (int nt = 0; nt < 2; ++nt) {
        zfs[nt] += __shfl_xor(zfs[nt], 16);
        zfs[nt] += __shfl_xor(zfs[nt], 32);
    }
    if (lq == 0) {
#pragma unroll
        for (int nt = 0; nt < 2; ++nt)
            zf1g[b * FF + w * 32 + nt * 16 + l15] = zfs[nt] * (1.f / 64.f);
    }
}

// ---------------------------------------------------------------------------
// Split-fp16 MFMA GEMM, N=256: C[M][256] = A[M][256] @ Wv[256][256].
// grid = (M/128)*2, 256 threads.
__global__ __launch_bounds__(256) void gemm_v(const float* __restrict__ A,
                                              const half_t* __restrict__ WTh,
                                              const half_t* __restrict__ WTl,
                                              float* __restrict__ C) {
    __shared__ float As[128][36];
    int bm = blockIdx.x >> 1;
    int bn = blockIdx.x & 1;
    int tid = threadIdx.x;
    int w = tid >> 6;
    int lane = tid & 63;
    int wr = w >> 1, wc = w & 1;
    int l15 = lane & 15;
    int lq  = lane >> 4;

    f32x4 acc[4][4];
#pragma unroll
    for (int i = 0; i < 4; ++i)
#pragma unroll
        for (int j = 0; j < 4; ++j) acc[i][j] = (f32x4){0.f, 0.f, 0.f, 0.f};

    const float* Ablk = A + (size_t)bm * 128 * 256;
    int colbase = bn * 128 + wc * 64;

    int srow = tid >> 1;
    int sseg = (tid & 1) * 16;

    for (int k0 = 0; k0 < 256; k0 += 32) {
        __syncthreads();
        {
            const float* src = Ablk + (size_t)srow * 256 + k0 + sseg;
            f32x4 v0 = *(const f32x4*)(src);
            f32x4 v1 = *(const f32x4*)(src + 4);
            f32x4 v2 = *(const f32x4*)(src + 8);
            f32x4 v3 = *(const f32x4*)(src + 12);
            *(f32x4*)&As[srow][sseg]      = v0;
            *(f32x4*)&As[srow][sseg + 4]  = v1;
            *(f32x4*)&As[srow][sseg + 8]  = v2;
            *(f32x4*)&As[srow][sseg + 12] = v3;
        }
        __syncthreads();

        half8 bh[4], bl[4];
#pragma unroll
        for (int tj = 0; tj < 4; ++tj) {
            size_t off = (size_t)(colbase + tj * 16 + l15) * 256 + k0 + lq * 8;
            bh[tj] = *(const half8*)(WTh + off);
            bl[tj] = *(const half8*)(WTl + off);
        }

        half8 ah[4], al[4];
#pragma unroll
        for (int ti = 0; ti < 4; ++ti) {
            const float* ap = &As[wr * 64 + ti * 16 + l15][lq * 8];
            f32x4 a0 = *(const f32x4*)(ap);
            f32x4 a1 = *(const f32x4*)(ap + 4);
#pragma unroll
            for (int j = 0; j < 4; ++j) {
                float x = a0[j];
                half_t h = (half_t)x;
                ah[ti][j] = h;
                al[ti][j] = (half_t)(x - (float)h);
            }
#pragma unroll
            for (int j = 0; j < 4; ++j) {
                float x = a1[j];
                half_t h = (half_t)x;
                ah[ti][4 + j] = h;
                al[ti][4 + j] = (half_t)(x - (float)h);
            }
        }

#pragma unroll
        for (int ti = 0; ti < 4; ++ti)
#pragma unroll
            for (int tj = 0; tj < 4; ++tj)
                acc[ti][tj] = __builtin_amdgcn_mfma_f32_16x16x32_f16(ah[ti], bh[tj], acc[ti][tj], 0, 0, 0);
#pragma unroll
        for (int ti = 0; ti < 4; ++ti)
#pragma unroll
            for (int tj = 0; tj < 4; ++tj)
                acc[ti][tj] = __builtin_amdgcn_mfma_f32_16x16x32_f16(ah[ti], bl[tj], acc[ti][tj], 0, 0, 0);
#pragma unroll
        for (int ti = 0; ti < 4; ++ti)
#pragma unroll
            for (int tj = 0; tj < 4; ++tj)
                acc[ti][tj] = __builtin_amdgcn_mfma_f32_16x16x32_f16(al[ti], bh[tj], acc[ti][tj], 0, 0, 0);
    }

    float* Cb = C + (size_t)(bm * 128 + wr * 64) * 256 + bn * 128 + wc * 64;
#pragma unroll
    for (int ti = 0; ti < 4; ++ti)
#pragma unroll
        for (int tj = 0; tj < 4; ++tj) {
            int r0 = ti * 16 + lq * 4;
            int c0 = tj * 16 + l15;
#pragma unroll
            for (int r = 0; r < 4; ++r)
                Cb[(size_t)(r0 + r) * 256 + c0] = acc[ti][tj][r];
        }
}

// ---------------------------------------------------------------------------
// Stack step (degenerate form) + mag: gates -> sigma -> mv recurrence ->
// read = sigma*mv -> zf2/pval -> mag partials. One block/batch, 256 thr.
__global__ __launch_bounds__(256) void k_stack3(
        const float* __restrict__ zf1,
        const float* __restrict__ ctrl_w, const float* __restrict__ ctrl_b,
        float* __restrict__ sigma, float* __restrict__ mv,
        const float* __restrict__ zfWv,
        float* __restrict__ readv, float* __restrict__ zf2,
        const float* __restrict__ halt_w, const float* __restrict__ halt_b,
        float* __restrict__ pval,
        const float* __restrict__ z, float* __restrict__ magpart) {
    __shared__ float zf[256];
    __shared__ float g[3];
    __shared__ float rd[256];
    __shared__ float red[256];

    int b = blockIdx.x, tid = threadIdx.x;
    int w = tid >> 6, lane = tid & 63;

    zf[tid] = zf1[b * FF + tid];
    __syncthreads();
    if (w < 3) {
        float s = 0.f;
#pragma unroll
        for (int q = 0; q < 4; ++q) {
            int c = lane + 64 * q;
            s += zf[c] * ctrl_w[c * 3 + w];
        }
#pragma unroll
        for (int off = 1; off < 64; off <<= 1) s += __shfl_xor(s, off);
        if (lane == 0) g[w] = 1.f / (1.f + expf(-(s + ctrl_b[w])));
    }
    __syncthreads();
    float tot = g[0] + g[1] + g[2] + 1e-6f;
    float push = g[0] / tot, pop = g[1] / tot, stay = g[2] / tot;
    float signew = sigma[b] * (push + pop + stay);   // sum(ptr) recurrence
    if (tid == 0) sigma[b] = signew;

    // mv recurrence (all 16 stack slots are identical -> single row state)
    float omp = 1.f - push;
    float m2v = mv[b * FF + tid] * omp + push * zfWv[b * FF + tid];
    mv[b * FF + tid] = m2v;

    // read = sigma * mv ; zf2 ; pval
    float a = signew * m2v;
    rd[tid] = a;
    readv[b * FF + tid] = a;
    float z2 = zf[tid] + 0.1f * a;
    zf2[b * FF + tid] = z2;
    red[tid] = z2 * halt_w[tid];
    __syncthreads();
    for (int off = 128; off > 0; off >>= 1) {
        if (tid < off) red[tid] += red[tid + off];
        __syncthreads();
    }
    if (tid == 0) pval[b] = 1.f / (1.f + expf(-(red[0] + halt_b[0])));
    __syncthreads();

    // mag sweep over z1 (+0.1*read)
    {
        int d = tid & 127, hf = tid >> 7;
        float rr = 0.1f * rd[d];
        float ri = 0.1f * rd[DD + d];
        const float* zb = z + (size_t)b * (SS * FF);
        float ms = 0.f, msq = 0.f;
        for (int s32 = 0; s32 < 32; ++s32) {
            int s = hf * 32 + s32;
            float zr = zb[s * FF + d] + rr;
            float zi = zb[s * FF + DD + d] + ri;
            float m2 = zr * zr + zi * zi;
            ms += sqrtf(m2); msq += m2;
        }
        red[tid] = ms;
        __syncthreads();
        for (int off = 128; off > 0; off >>= 1) {
            if (tid < off) red[tid] += red[tid + off];
            __syncthreads();
        }
        float tms = red[0];
        __syncthreads();
        red[tid] = msq;
        __syncthreads();
        for (int off = 128; off > 0; off >>= 1) {
            if (tid < off) red[tid] += red[tid + off];
            __syncthreads();
        }
        if (tid == 0) { magpart[2 * b] = tms; magpart[2 * b + 1] = red[0]; }
    }
}

// ---------------------------------------------------------------------------
// Lean VQ kernel (unchanged from R11).
__global__ __launch_bounds__(256) void k_vq2(
        const float* __restrict__ zf2g, const float* __restrict__ readv,
        float* __restrict__ probs, float* __restrict__ halt,
        const float* __restrict__ pvalg, const float* __restrict__ magp,
        const float* __restrict__ cb, const float* __restrict__ cb2,
        const float* __restrict__ adj,
        float* __restrict__ delta, float* __restrict__ wact, int t) {
    __shared__ float zf[256];
    __shared__ float pr[128];
    __shared__ float upred[8];
    __shared__ float zzred[4];
    __shared__ float mxred[4];
    __shared__ float sered[4];

    int b = blockIdx.x, tid = threadIdx.x;
    int w = tid >> 6, lane = tid & 63;

    zf[tid] = zf2g[b * FF + tid];

    float up = 0.f;
    if (t > 0) {
        f32x4 mv4 = *(const f32x4*)(magp + tid * 4);
        float pa = mv4[0] + mv4[2];
        float pb = mv4[1] + mv4[3];
#pragma unroll
        for (int off = 1; off < 64; off <<= 1) {
            pa += __shfl_xor(pa, off);
            pb += __shfl_xor(pb, off);
        }
        if (lane == 0) { upred[w * 2] = pa; upred[w * 2 + 1] = pb; }
    }
    __syncthreads();
    if (t > 0) {
        float tms  = upred[0] + upred[2] + upred[4] + upred[6];
        float tmsq = upred[1] + upred[3] + upred[5] + upred[7];
        const float N = 4194304.f;   // B*S*D
        float mean = tms / N;
        float var = tmsq / N - mean * mean;
        float x = var / (1.f + 1e-6f);
        up = (x > 20.f) ? x : log1pf(expf(x));
    }

    {
        float part = zf[tid] * zf[tid];
#pragma unroll
        for (int off = 1; off < 64; off <<= 1) part += __shfl_xor(part, off);
        if (lane == 0) zzred[w] = part;
    }
    __syncthreads();
    float zz = zzred[0] + zzred[1] + zzred[2] + zzred[3];

    int n = tid >> 1, half = tid & 1;
    float dacc = 0.f;
    {
        const float* cbn = cb + n * FF + half * 128;
        const float* zfp = zf + half * 128;
#pragma unroll 8
        for (int c2 = 0; c2 < 128; c2 += 4) {
            f32x4 cv = *(const f32x4*)(cbn + c2);
            dacc += cv[0] * zfp[c2] + cv[1] * zfp[c2 + 1] + cv[2] * zfp[c2 + 2] + cv[3] * zfp[c2 + 3];
        }
        dacc += __shfl_xor(dacc, 1);
    }
    float gacc = 0.f;
    if (t > 0) {
        const float* pp = probs + b * NSYM;
        for (int k = half * 64; k < half * 64 + 64; ++k)
            gacc += pp[k] * adj[k * NSYM + n];
        gacc += __shfl_xor(gacc, 1);
    }

    float dist = (zz + cb2[n] - 2.f * dacc) * (1.f / 256.f);
    float dtot = dist;
    if (t > 0) dtot = dist - 0.01f * up * (1.f / (1.f + expf(-gacc)));
    float vval = -dtot;   // TEMP = 1

    {
        float m = vval;
#pragma unroll
        for (int off = 1; off < 64; off <<= 1) m = fmaxf(m, __shfl_xor(m, off));
        if (lane == 0) mxred[w] = m;
    }
    __syncthreads();
    float mx = fmaxf(fmaxf(mxred[0], mxred[1]), fmaxf(mxred[2], mxred[3]));

    float e = expf(vval - mx);
    {
        float s = (half == 0) ? e : 0.f;
#pragma unroll
        for (int off = 1; off < 64; off <<= 1) s += __shfl_xor(s, off);
        if (lane == 0) sered[w] = s;
    }
    __syncthreads();
    float se = sered[0] + sered[1] + sered[2] + sered[3];
    float psm = e / se;
    if (half == 0) {
        pr[n] = psm;
        probs[b * NSYM + n] = psm;
    }
    __syncthreads();

    float q = 0.f;
#pragma unroll 4
    for (int k = 0; k < NSYM; ++k) q += pr[k] * cb[k * FF + tid];
    delta[b * FF + tid] = readv[b * FF + tid] + q;

    if (tid == 0) {
        float h = halt[b], p = pvalg[b];
        float running = (h < 0.99f) ? 1.f : 0.f;
        float w2 = (((h + p * running) >= 0.99f) ? (1.f - h) : p) * running;
        halt[b] = h + w2;
        wact[b] = w2;
    }
}

// ---------------------------------------------------------------------------
// Final deferred delta + ACT accumulation.
__global__ __launch_bounds__(256) void k_epilogue(const float* __restrict__ z,
                                                  const float* __restrict__ delta,
                                                  const float* __restrict__ wact,
                                                  float* __restrict__ acc) {
    int idx = blockIdx.x * 256 + threadIdx.x;   // grid 32768 -> 8388608
    int b = idx >> 14;
    int c = idx & 255;
    float wa = wact[b];
    if (wa != 0.0f)
        acc[idx] += wa * (z[idx] + 0.1f * delta[b * FF + c]);
}

// ---------------------------------------------------------------------------
extern "C" void kernel_launch(void* const* d_in, const int* in_sizes, int n_in,
                              void* d_out, int out_size, void* d_ws, size_t ws_size,
                              hipStream_t stream) {
    const float* z_real  = (const float*)d_in[0];
    const float* z_imag  = (const float*)d_in[1];
    const float* attn_wr = (const float*)d_in[2];
    const float* attn_wi = (const float*)d_in[3];
    const float* mem_wr  = (const float*)d_in[4];
    const float* mem_wi  = (const float*)d_in[5];
    const float* ctrl_w  = (const float*)d_in[6];
    const float* ctrl_b  = (const float*)d_in[7];
    const float* halt_w  = (const float*)d_in[8];
    const float* halt_b  = (const float*)d_in[9];
    const float* codebook  = (const float*)d_in[10];
    const float* adjacency = (const float*)d_in[11];

    float* ws = (float*)d_ws;
    float* z      = ws + Z_OFF;
    float* WT32   = ws + QKV_OFF;
    half_t* GTh   = (half_t*)(ws + QKV_OFF + 196608);
    half_t* GTl   = GTh + 65536;
    half_t* WvTh  = GTl + 65536;
    half_t* WvTl  = WvTh + 65536;
    float* zfWv   = ws + ZFW_OFF;                       // 131072
    half_t* MvTh  = (half_t*)(ws + ZFW_OFF + 131072);   // 65536 halfs
    half_t* MvTl  = MvTh + 65536;
    float* mv     = ws + MV_OFF;
    float* sigma  = ws + SIG_OFF;
    float* zf1    = ws + ZF1_OFF;
    float* zf2    = ws + ZF2_OFF;
    float* readv  = ws + READ_OFF;
    float* probs  = ws + PROBS_OFF;
    float* delta  = ws + DELTA_OFF;
    float* halt   = ws + HALT_OFF;
    float* pval   = ws + PVAL_OFF;
    float* wact   = ws + WACT_OFF;
    float* magp   = ws + MAGP_OFF;
    float* MT32   = ws + MQKV_OFF;
    float* cb2    = ws + CB2_OFF;
    float* acc    = (float*)d_out;

    k_buildwt32<<<768, 256, 0, stream>>>(attn_wr, attn_wi, WT32);
    k_buildG<<<256, 256, 0, stream>>>(WT32, GTh, GTl);
    k_splitWv<<<256, 256, 0, stream>>>(WT32, WvTh, WvTl);
    k_buildwt32<<<768, 256, 0, stream>>>(mem_wr, mem_wi, MT32);
    k_splitWv<<<256, 256, 0, stream>>>(MT32, MvTh, MvTl);
    k_cb2<<<1, 128, 0, stream>>>(codebook, cb2);
    k_init<<<32768, 256, 0, stream>>>(z_real, z_imag, z, mv, sigma, halt, acc,
                                      delta, wact);

    for (int t = 0; t < NDEPTH; ++t) {
        k_attn8<<<BB, 512, 0, stream>>>(z, GTh, GTl, WvTh, WvTl, delta, wact, acc, zf1);
        gemm_v<<<8, 256, 0, stream>>>(zf1, MvTh, MvTl, zfWv);
        k_stack3<<<BB, 256, 0, stream>>>(zf1, ctrl_w, ctrl_b, sigma, mv, zfWv,
                                         readv, zf2, halt_w, halt_b, pval, z, magp);
        k_vq2<<<BB, 256, 0, stream>>>(zf2, readv, probs, halt, pval, magp,
                                      codebook, cb2, adjacency, delta, wact, t);
    }
    k_epilogue<<<32768, 256, 0, stream>>>(z, delta, wact, acc);
}

// Round 13
// 781.662 us; speedup vs baseline: 5.1361x; 1.0721x over previous
//
#include <hip/hip_runtime.h>
#include <math.h>

// Problem constants
#define BB 512
#define SS 64
#define DD 128
#define FF 256   // 2D
#define NSYM 128
#define STK 16
#define NDEPTH 8

typedef _Float16 half_t;
typedef __attribute__((ext_vector_type(4))) _Float16 half4;
typedef __attribute__((ext_vector_type(8))) _Float16 half8;
typedef __attribute__((ext_vector_type(4))) float f32x4;

// Workspace offsets (in floats)
#define Z_OFF      0ull                    // B*S*F      = 8388608
#define QKV_OFF    8388608ull              // WT32 + GT/WvT split planes (attn)
#define WVM_OFF    33554432ull             // Wv32m [e][c] = 65536
#define MV_OFF     35651584ull             // mv state B*256 = 131072
#define SIG_OFF    35782656ull             // sigma B = 512
#define ZF1_OFF    41951232ull             // B*256      = 131072
#define ZF2_OFF    42082304ull             // B*256      = 131072
#define READ_OFF   42213376ull             // B*256      = 131072
#define PROBS_OFF  42344448ull             // B*128      = 65536
#define DELTA_OFF  42409984ull             // B*256      = 131072 (read + quant)
#define HALT_OFF   42541056ull             // B          = 512
#define PVAL_OFF   42541568ull             // B          = 512
#define WACT_OFF   42542080ull             // B          = 512
#define MAGP_OFF   42542592ull             // B*2        = 1024
#define CB2_OFF    42936832ull             // 128

// ---------------------------------------------------------------------------
// Combined transposed weight, fp32: WT32[col=h*256+c][e] = W_h[e][c]
__global__ void k_buildwt32(const float* __restrict__ wr, const float* __restrict__ wi,
                            float* __restrict__ WT32) {
    int idx = blockIdx.x * 256 + threadIdx.x;   // 196608 total, grid=768
    if (idx >= 768 * 256) return;
    int col = idx >> 8;
    int e   = idx & 255;
    int h   = col >> 8;
    int c   = col & 255;
    const float* Wr = wr + h * DD * DD;
    const float* Wi = wi + h * DD * DD;
    float v;
    if (c < DD) {
        v = (e < DD) ? Wr[c * DD + e] : -Wi[c * DD + (e - DD)];
    } else {
        int j = c - DD;
        v = (e < DD) ? Wi[j * DD + e] : Wr[j * DD + (e - DD)];
    }
    WT32[idx] = v;
}

// GT[n][e] = G[e][n] = sum_c Wq[e][c]*Wk[n][c], split to fp16 h/l (unscaled).
__global__ __launch_bounds__(256) void k_buildG(const float* __restrict__ WT32,
                                                half_t* __restrict__ GTh,
                                                half_t* __restrict__ GTl) {
    __shared__ float kcol[256];
    int n = blockIdx.x;
    int e = threadIdx.x;
    kcol[e] = WT32[65536 + e * 256 + n];   // Wk[n][c=e]
    __syncthreads();
    float s = 0.f;
    for (int c = 0; c < 256; ++c) s += kcol[c] * WT32[c * 256 + e];  // Wq[e][c]
    half_t h = (half_t)s;
    GTh[n * 256 + e] = h;
    GTl[n * 256 + e] = (half_t)(s - (float)h);
}

// Split the attn V-head columns (cols 512..767 of WT32) to fp16 h/l (transposed).
__global__ void k_splitWv(const float* __restrict__ WT32,
                          half_t* __restrict__ WvTh, half_t* __restrict__ WvTl) {
    int idx = blockIdx.x * 256 + threadIdx.x;   // 65536, grid 256
    float v = WT32[131072 + idx];   // WvT[n][e]
    half_t h = (half_t)v;
    WvTh[idx] = h;
    WvTl[idx] = (half_t)(v - (float)h);
}

// Mem-path V weight in [e][c] fp32 layout (c contiguous -> coalesced dots).
__global__ void k_buildWv32m(const float* __restrict__ wr, const float* __restrict__ wi,
                             float* __restrict__ Wv32m) {
    int idx = blockIdx.x * 256 + threadIdx.x;   // 65536, grid 256
    int e = idx >> 8;
    int c = idx & 255;
    const float* Wr = wr + 2 * DD * DD;   // V head
    const float* Wi = wi + 2 * DD * DD;
    float v;
    if (c < DD) {
        v = (e < DD) ? Wr[c * DD + e] : -Wi[c * DD + (e - DD)];
    } else {
        int j = c - DD;
        v = (e < DD) ? Wi[j * DD + e] : Wr[j * DD + (e - DD)];
    }
    Wv32m[idx] = v;
}

__global__ void k_cb2(const float* __restrict__ cb, float* __restrict__ cb2) {
    int n = threadIdx.x;   // 128 threads
    float s = 0.f;
    for (int c = 0; c < FF; ++c) { float v = cb[n * FF + c]; s += v * v; }
    cb2[n] = s;
}

__global__ __launch_bounds__(256) void k_init(const float* __restrict__ zr_in,
                                              const float* __restrict__ zi_in,
                                              float* __restrict__ z, float* __restrict__ mv,
                                              float* __restrict__ sigma,
                                              float* __restrict__ halt, float* __restrict__ acc,
                                              float* __restrict__ delta, float* __restrict__ wact) {
    size_t idx = (size_t)blockIdx.x * 256 + threadIdx.x;  // grid 32768 -> 8388608
    int c = (int)(idx & 255);
    size_t bs = idx >> 8;
    z[idx] = (c < DD) ? zr_in[bs * DD + c] : zi_in[bs * DD + (c - DD)];
    acc[idx] = 0.f;
    if (idx < 131072) { mv[idx] = 0.f; delta[idx] = 0.f; }
    if (idx < 512)   { halt[idx] = 0.f; wact[idx] = 0.f; sigma[idx] = 1.f; }
}

// ---------------------------------------------------------------------------
// Fused attention step. 8 waves, 1 blk/CU. Phase B: S split over all 8 waves
// (j-halves) with online-softmax merge after sync3 (no extra barriers).
__global__ __launch_bounds__(512, 1) void k_attn8(
        float* __restrict__ z,
        const half_t* __restrict__ GTh, const half_t* __restrict__ GTl,
        const half_t* __restrict__ WvTh, const half_t* __restrict__ WvTl,
        const float* __restrict__ delta, const float* __restrict__ wact,
        float* __restrict__ acc, float* __restrict__ zf1g) {
    __shared__ half_t Zh[16896];         // 64 x 264, 33 KB
    __shared__ half_t Zl[16896];
    __shared__ half_t Ubuf[2][18432];    // union: T[64][264] / VT[256][72]
    __shared__ half_t Pbuf[2][4][1152];
    __shared__ float Smx[4][2][16];      // per-query partial softmax stats
    __shared__ float Ssum[4][2][16];

    int b = blockIdx.x, tid = threadIdx.x;
    int w = tid >> 6, lane = tid & 63;
    int l15 = lane & 15, lq = lane >> 4;
    float* zb = z + (size_t)b * (SS * FF);
    float* accb = acc + (size_t)b * (SS * FF);

    // ---- phase 0: x0 = z + 0.1*delta; deferred acc; split to LDS
    float wa = wact[b];
    f32x4 dv = *(const f32x4*)(delta + b * FF + lane * 4);
    bool doacc = (wa != 0.0f);
#pragma unroll
    for (int it = 0; it < 8; ++it) {
        int i = w * 8 + it;
        f32x4 zv = *(const f32x4*)(zb + (size_t)i * FF + lane * 4);
        f32x4 x0;
#pragma unroll
        for (int jj = 0; jj < 4; ++jj) x0[jj] = zv[jj] + 0.1f * dv[jj];
        if (doacc) {
            f32x4 av = *(const f32x4*)(accb + (size_t)i * FF + lane * 4);
#pragma unroll
            for (int jj = 0; jj < 4; ++jj) av[jj] += wa * x0[jj];
            *(f32x4*)(accb + (size_t)i * FF + lane * 4) = av;
        }
        half4 h4, l4;
#pragma unroll
        for (int jj = 0; jj < 4; ++jj) {
            half_t h = (half_t)x0[jj];
            h4[jj] = h; l4[jj] = (half_t)(x0[jj] - (float)h);
        }
        *(half4*)&Zh[i * 264 + lane * 4] = h4;
        *(half4*)&Zl[i * 264 + lane * 4] = l4;
    }
    __syncthreads();   // sync 1: Z staged

    // ---- phase T: T = x0 @ G, wave w owns 32-col band.
    {
        f32x4 tac[4][2];
#pragma unroll
        for (int mt = 0; mt < 4; ++mt)
#pragma unroll
            for (int nt = 0; nt < 2; ++nt) tac[mt][nt] = (f32x4){0.f, 0.f, 0.f, 0.f};
        __builtin_amdgcn_s_setprio(1);
#pragma unroll 2
        for (int kt = 0; kt < 8; ++kt) {
            int kc = kt * 32 + lq * 8;
            half8 ah[4], al[4], gh[2], gl[2];
#pragma unroll
            for (int mt = 0; mt < 4; ++mt) {
                int ro = (mt * 16 + l15) * 264 + kc;
                ah[mt] = *(const half8*)&Zh[ro];
                al[mt] = *(const half8*)&Zl[ro];
            }
#pragma unroll
            for (int nt = 0; nt < 2; ++nt) {
                size_t go = (size_t)(w * 32 + nt * 16 + l15) * 256 + kc;
                gh[nt] = *(const half8*)(GTh + go);
                gl[nt] = *(const half8*)(GTl + go);
            }
#pragma unroll
            for (int mt = 0; mt < 4; ++mt)
#pragma unroll
                for (int nt = 0; nt < 2; ++nt) {
                    tac[mt][nt] = __builtin_amdgcn_mfma_f32_16x16x32_f16(ah[mt], gh[nt], tac[mt][nt], 0, 0, 0);
                    tac[mt][nt] = __builtin_amdgcn_mfma_f32_16x16x32_f16(ah[mt], gl[nt], tac[mt][nt], 0, 0, 0);
                    tac[mt][nt] = __builtin_amdgcn_mfma_f32_16x16x32_f16(al[mt], gh[nt], tac[mt][nt], 0, 0, 0);
                }
        }
        __builtin_amdgcn_s_setprio(0);
        const float scale = 0.08838834764831845f;
#pragma unroll
        for (int mt = 0; mt < 4; ++mt)
#pragma unroll
            for (int nt = 0; nt < 2; ++nt)
#pragma unroll
                for (int r = 0; r < 4; ++r) {
                    int m = mt * 16 + lq * 4 + r;
                    int n = w * 32 + nt * 16 + l15;
                    float v = tac[mt][nt][r] * scale;
                    half_t h = (half_t)v;
                    Ubuf[0][m * 264 + n] = h;
                    Ubuf[1][m * 264 + n] = (half_t)(v - (float)h);
                }
    }
    __syncthreads();   // sync 2: T ready

    // ---- phase B: all 8 waves: S half (48 MFMA) -> partial stats; then V band.
    int qb = w & 3;    // query band
    int jh = w >> 2;   // j half
    float sv[2][4];
    {
        f32x4 sac[2];
        sac[0] = (f32x4){0.f, 0.f, 0.f, 0.f};
        sac[1] = (f32x4){0.f, 0.f, 0.f, 0.f};
        __builtin_amdgcn_s_setprio(1);
#pragma unroll 2
        for (int kt = 0; kt < 8; ++kt) {
            int kc = kt * 32 + lq * 8;
            int to = (qb * 16 + l15) * 264 + kc;
            half8 bh = *(const half8*)&Ubuf[0][to];
            half8 bl = *(const half8*)&Ubuf[1][to];
            half8 ah[2], al[2];
#pragma unroll
            for (int jt = 0; jt < 2; ++jt) {
                int ro = ((jh * 2 + jt) * 16 + l15) * 264 + kc;
                ah[jt] = *(const half8*)&Zh[ro];
                al[jt] = *(const half8*)&Zl[ro];
            }
#pragma unroll
            for (int jt = 0; jt < 2; ++jt) {
                sac[jt] = __builtin_amdgcn_mfma_f32_16x16x32_f16(ah[jt], bh, sac[jt], 0, 0, 0);
                sac[jt] = __builtin_amdgcn_mfma_f32_16x16x32_f16(ah[jt], bl, sac[jt], 0, 0, 0);
                sac[jt] = __builtin_amdgcn_mfma_f32_16x16x32_f16(al[jt], bh, sac[jt], 0, 0, 0);
            }
        }
        __builtin_amdgcn_s_setprio(0);
        float mxh = -1e30f;
#pragma unroll
        for (int jt = 0; jt < 2; ++jt)
#pragma unroll
            for (int r = 0; r < 4; ++r) { sv[jt][r] = sac[jt][r]; mxh = fmaxf(mxh, sv[jt][r]); }
        mxh = fmaxf(mxh, __shfl_xor(mxh, 16));
        mxh = fmaxf(mxh, __shfl_xor(mxh, 32));
        float sumh = 0.f;
#pragma unroll
        for (int jt = 0; jt < 2; ++jt)
#pragma unroll
            for (int r = 0; r < 4; ++r) { float e = expf(sv[jt][r] - mxh); sv[jt][r] = e; sumh += e; }
        sumh += __shfl_xor(sumh, 16);
        sumh += __shfl_xor(sumh, 32);
        if (lq == 0) { Smx[qb][jh][l15] = mxh; Ssum[qb][jh][l15] = sumh; }
    }

    // V band (all waves, 32 cols each)
    f32x4 vac[4][2];
#pragma unroll
    for (int mt = 0; mt < 4; ++mt)
#pragma unroll
        for (int nt = 0; nt < 2; ++nt) vac[mt][nt] = (f32x4){0.f, 0.f, 0.f, 0.f};
    __builtin_amdgcn_s_setprio(1);
#pragma unroll 2
    for (int kt = 0; kt < 8; ++kt) {
        int kc = kt * 32 + lq * 8;
        half8 ah[4], al[4], gh[2], gl[2];
#pragma unroll
        for (int mt = 0; mt < 4; ++mt) {
            int ro = (mt * 16 + l15) * 264 + kc;
            ah[mt] = *(const half8*)&Zh[ro];
            al[mt] = *(const half8*)&Zl[ro];
        }
#pragma unroll
        for (int nt = 0; nt < 2; ++nt) {
            size_t go = (size_t)(w * 32 + nt * 16 + l15) * 256 + kc;
            gh[nt] = *(const half8*)(WvTh + go);
            gl[nt] = *(const half8*)(WvTl + go);
        }
#pragma unroll
        for (int mt = 0; mt < 4; ++mt)
#pragma unroll
            for (int nt = 0; nt < 2; ++nt) {
                vac[mt][nt] = __builtin_amdgcn_mfma_f32_16x16x32_f16(ah[mt], gh[nt], vac[mt][nt], 0, 0, 0);
                vac[mt][nt] = __builtin_amdgcn_mfma_f32_16x16x32_f16(ah[mt], gl[nt], vac[mt][nt], 0, 0, 0);
                vac[mt][nt] = __builtin_amdgcn_mfma_f32_16x16x32_f16(al[mt], gh[nt], vac[mt][nt], 0, 0, 0);
            }
    }
    __builtin_amdgcn_s_setprio(0);
    __syncthreads();   // sync 3: S+T reads done, stats visible

    // finalize softmax (online merge) + write P for this wave's j half
    {
        float mx0 = Smx[qb][0][l15], mx1 = Smx[qb][1][l15];
        float gmx = fmaxf(mx0, mx1);
        float ssum = Ssum[qb][0][l15] * expf(mx0 - gmx) + Ssum[qb][1][l15] * expf(mx1 - gmx);
        float pscale = expf(((jh == 0) ? mx0 : mx1) - gmx) / ssum;
#pragma unroll
        for (int jt = 0; jt < 2; ++jt) {
            half4 h4, l4;
#pragma unroll
            for (int r = 0; r < 4; ++r) {
                float pv = sv[jt][r] * pscale;
                half_t hh = (half_t)pv;
                h4[r] = hh;
                l4[r] = (half_t)(pv - (float)hh);
            }
            int po = l15 * 72 + (jh * 2 + jt) * 16 + lq * 4;
            *(half4*)&Pbuf[0][qb][po] = h4;
            *(half4*)&Pbuf[1][qb][po] = l4;
        }
    }

    // VT write
#pragma unroll
    for (int mt = 0; mt < 4; ++mt)
#pragma unroll
        for (int nt = 0; nt < 2; ++nt) {
            int n = w * 32 + nt * 16 + l15;
            int m0 = mt * 16 + lq * 4;
            half4 h4, l4;
#pragma unroll
            for (int r = 0; r < 4; ++r) {
                float v = vac[mt][nt][r];
                half_t h = (half_t)v;
                h4[r] = h; l4[r] = (half_t)(v - (float)h);
            }
            *(half4*)&Ubuf[0][n * 72 + m0] = h4;
            *(half4*)&Ubuf[1][n * 72 + m0] = l4;
        }
    __syncthreads();   // sync 4: VT + P visible

    // ---- phase O
    f32x4 oc[4][2];
#pragma unroll
    for (int mt = 0; mt < 4; ++mt)
#pragma unroll
        for (int nt = 0; nt < 2; ++nt) oc[mt][nt] = (f32x4){0.f, 0.f, 0.f, 0.f};
    __builtin_amdgcn_s_setprio(1);
#pragma unroll
    for (int kt = 0; kt < 2; ++kt) {
        half8 pah[4], pal[4];
#pragma unroll
        for (int mt = 0; mt < 4; ++mt) {
            int po = l15 * 72 + kt * 32 + lq * 8;
            pah[mt] = *(const half8*)&Pbuf[0][mt][po];
            pal[mt] = *(const half8*)&Pbuf[1][mt][po];
        }
#pragma unroll
        for (int nt = 0; nt < 2; ++nt) {
            int n = w * 32 + nt * 16 + l15;
            half8 vbh = *(const half8*)&Ubuf[0][n * 72 + kt * 32 + lq * 8];
            half8 vbl = *(const half8*)&Ubuf[1][n * 72 + kt * 32 + lq * 8];
#pragma unroll
            for (int mt = 0; mt < 4; ++mt) {
                oc[mt][nt] = __builtin_amdgcn_mfma_f32_16x16x32_f16(pah[mt], vbh, oc[mt][nt], 0, 0, 0);
                oc[mt][nt] = __builtin_amdgcn_mfma_f32_16x16x32_f16(pah[mt], vbl, oc[mt][nt], 0, 0, 0);
                oc[mt][nt] = __builtin_amdgcn_mfma_f32_16x16x32_f16(pal[mt], vbh, oc[mt][nt], 0, 0, 0);
            }
        }
    }
    __builtin_amdgcn_s_setprio(0);

    // ---- epilogue: z_out = O + 0.1*x0; zf1 col-means for this wave's band
    float zfs[2] = {0.f, 0.f};
#pragma unroll
    for (int mt = 0; mt < 4; ++mt)
#pragma unroll
        for (int nt = 0; nt < 2; ++nt)
#pragma unroll
            for (int r = 0; r < 4; ++r) {
                int i = mt * 16 + lq * 4 + r;
                int c = w * 32 + nt * 16 + l15;
                int zo = i * 264 + c;
                float x0 = (float)Zh[zo] + (float)Zl[zo];
                float z1 = oc[mt][nt][r] + 0.1f * x0;
                zb[(size_t)i * FF + c] = z1;
                zfs[nt] += z1;
            }
#pragma unroll
    for (int nt = 0; nt < 2; ++nt) {
        zfs[nt] += __shfl_xor(zfs[nt], 16);
        zfs[nt] += __shfl_xor(zfs[nt], 32);
    }
    if (lq == 0) {
#pragma unroll
        for (int nt = 0; nt < 2; ++nt)
            zf1g[b * FF + w * 32 + nt * 16 + l15] = zfs[nt] * (1.f / 64.f);
    }
}

// ---------------------------------------------------------------------------
// Stack step (degenerate) + fused zfWv vec-mat + mag. One block/batch, 256 thr.
__global__ __launch_bounds__(256) void k_stack3(
        const float* __restrict__ zf1,
        const float* __restrict__ ctrl_w, const float* __restrict__ ctrl_b,
        float* __restrict__ sigma, float* __restrict__ mv,
        const float* __restrict__ Wv32m,
        float* __restrict__ readv, float* __restrict__ zf2,
        const float* __restrict__ halt_w, const float* __restrict__ halt_b,
        float* __restrict__ pval,
        const float* __restrict__ z, float* __restrict__ magpart) {
    __shared__ float zf[256];
    __shared__ float g[3];
    __shared__ float rd[256];
    __shared__ float red[256];

    int b = blockIdx.x, tid = threadIdx.x;
    int w = tid >> 6, lane = tid & 63;

    zf[tid] = zf1[b * FF + tid];
    __syncthreads();

    // zfWv[c=tid] = zf1[b] . Wv_mem[:,c]  (coalesced [e][c] stream, exact fp32)
    float zw = 0.f;
#pragma unroll 8
    for (int e = 0; e < 256; ++e) zw += Wv32m[e * 256 + tid] * zf[e];

    if (w < 3) {
        float s = 0.f;
#pragma unroll
        for (int q = 0; q < 4; ++q) {
            int c = lane + 64 * q;
            s += zf[c] * ctrl_w[c * 3 + w];
        }
#pragma unroll
        for (int off = 1; off < 64; off <<= 1) s += __shfl_xor(s, off);
        if (lane == 0) g[w] = 1.f / (1.f + expf(-(s + ctrl_b[w])));
    }
    __syncthreads();
    float tot = g[0] + g[1] + g[2] + 1e-6f;
    float push = g[0] / tot, pop = g[1] / tot, stay = g[2] / tot;
    float signew = sigma[b] * (push + pop + stay);   // sum(ptr) recurrence
    if (tid == 0) sigma[b] = signew;

    // mv recurrence (all 16 stack slots identical -> single row state)
    float omp = 1.f - push;
    float m2v = mv[b * FF + tid] * omp + push * zw;
    mv[b * FF + tid] = m2v;

    // read = sigma * mv ; zf2 ; pval
    float a = signew * m2v;
    rd[tid] = a;
    readv[b * FF + tid] = a;
    float z2 = zf[tid] + 0.1f * a;
    zf2[b * FF + tid] = z2;
    red[tid] = z2 * halt_w[tid];
    __syncthreads();
    for (int off = 128; off > 0; off >>= 1) {
        if (tid < off) red[tid] += red[tid + off];
        __syncthreads();
    }
    if (tid == 0) pval[b] = 1.f / (1.f + expf(-(red[0] + halt_b[0])));
    __syncthreads();

    // mag sweep over z1 (+0.1*read)
    {
        int d = tid & 127, hf = tid >> 7;
        float rr = 0.1f * rd[d];
        float ri = 0.1f * rd[DD + d];
        const float* zb = z + (size_t)b * (SS * FF);
        float ms = 0.f, msq = 0.f;
        for (int s32 = 0; s32 < 32; ++s32) {
            int s = hf * 32 + s32;
            float zr = zb[s * FF + d] + rr;
            float zi = zb[s * FF + DD + d] + ri;
            float m2 = zr * zr + zi * zi;
            ms += sqrtf(m2); msq += m2;
        }
        red[tid] = ms;
        __syncthreads();
        for (int off = 128; off > 0; off >>= 1) {
            if (tid < off) red[tid] += red[tid + off];
            __syncthreads();
        }
        float tms = red[0];
        __syncthreads();
        red[tid] = msq;
        __syncthreads();
        for (int off = 128; off > 0; off >>= 1) {
            if (tid < off) red[tid] += red[tid + off];
            __syncthreads();
        }
        if (tid == 0) { magpart[2 * b] = tms; magpart[2 * b + 1] = red[0]; }
    }
}

// ---------------------------------------------------------------------------
// Lean VQ kernel; when last!=0 also performs the final ACT accumulation.
__global__ __launch_bounds__(256) void k_vq2(
        const float* __restrict__ zf2g, const float* __restrict__ readv,
        float* __restrict__ probs, float* __restrict__ halt,
        const float* __restrict__ pvalg, const float* __restrict__ magp,
        const float* __restrict__ cb, const float* __restrict__ cb2,
        const float* __restrict__ adj,
        float* __restrict__ delta, float* __restrict__ wact,
        const float* __restrict__ z, float* __restrict__ acc,
        int t, int last) {
    __shared__ float zf[256];
    __shared__ float pr[128];
    __shared__ float upred[8];
    __shared__ float zzred[4];
    __shared__ float mxred[4];
    __shared__ float sered[4];
    __shared__ float waS[1];

    int b = blockIdx.x, tid = threadIdx.x;
    int w = tid >> 6, lane = tid & 63;

    zf[tid] = zf2g[b * FF + tid];

    float up = 0.f;
    if (t > 0) {
        f32x4 mv4 = *(const f32x4*)(magp + tid * 4);
        float pa = mv4[0] + mv4[2];
        float pb = mv4[1] + mv4[3];
#pragma unroll
        for (int off = 1; off < 64; off <<= 1) {
            pa += __shfl_xor(pa, off);
            pb += __shfl_xor(pb, off);
        }
        if (lane == 0) { upred[w * 2] = pa; upred[w * 2 + 1] = pb; }
    }
    __syncthreads();
    if (t > 0) {
        float tms  = upred[0] + upred[2] + upred[4] + upred[6];
        float tmsq = upred[1] + upred[3] + upred[5] + upred[7];
        const float N = 4194304.f;   // B*S*D
        float mean = tms / N;
        float var = tmsq / N - mean * mean;
        float x = var / (1.f + 1e-6f);
        up = (x > 20.f) ? x : log1pf(expf(x));
    }

    {
        float part = zf[tid] * zf[tid];
#pragma unroll
        for (int off = 1; off < 64; off <<= 1) part += __shfl_xor(part, off);
        if (lane == 0) zzred[w] = part;
    }
    __syncthreads();
    float zz = zzred[0] + zzred[1] + zzred[2] + zzred[3];

    int n = tid >> 1, half = tid & 1;
    float dacc = 0.f;
    {
        const float* cbn = cb + n * FF + half * 128;
        const float* zfp = zf + half * 128;
#pragma unroll 8
        for (int c2 = 0; c2 < 128; c2 += 4) {
            f32x4 cv = *(const f32x4*)(cbn + c2);
            dacc += cv[0] * zfp[c2] + cv[1] * zfp[c2 + 1] + cv[2] * zfp[c2 + 2] + cv[3] * zfp[c2 + 3];
        }
        dacc += __shfl_xor(dacc, 1);
    }
    float gacc = 0.f;
    if (t > 0) {
        const float* pp = probs + b * NSYM;
        for (int k = half * 64; k < half * 64 + 64; ++k)
            gacc += pp[k] * adj[k * NSYM + n];
        gacc += __shfl_xor(gacc, 1);
    }

    float dist = (zz + cb2[n] - 2.f * dacc) * (1.f / 256.f);
    float dtot = dist;
    if (t > 0) dtot = dist - 0.01f * up * (1.f / (1.f + expf(-gacc)));
    float vval = -dtot;   // TEMP = 1

    {
        float m = vval;
#pragma unroll
        for (int off = 1; off < 64; off <<= 1) m = fmaxf(m, __shfl_xor(m, off));
        if (lane == 0) mxred[w] = m;
    }
    __syncthreads();
    float mx = fmaxf(fmaxf(mxred[0], mxred[1]), fmaxf(mxred[2], mxred[3]));

    float e = expf(vval - mx);
    {
        float s = (half == 0) ? e : 0.f;
#pragma unroll
        for (int off = 1; off < 64; off <<= 1) s += __shfl_xor(s, off);
        if (lane == 0) sered[w] = s;
    }
    __syncthreads();
    float se = sered[0] + sered[1] + sered[2] + sered[3];
    float psm = e / se;
    if (half == 0) {
        pr[n] = psm;
        probs[b * NSYM + n] = psm;
    }
    __syncthreads();

    float q = 0.f;
#pragma unroll 4
    for (int k = 0; k < NSYM; ++k) q += pr[k] * cb[k * FF + tid];
    float dltc = readv[b * FF + tid] + q;
    delta[b * FF + tid] = dltc;

    if (tid == 0) {
        float h = halt[b], p = pvalg[b];
        float running = (h < 0.99f) ? 1.f : 0.f;
        float w2 = (((h + p * running) >= 0.99f) ? (1.f - h) : p) * running;
        halt[b] = h + w2;
        wact[b] = w2;
        waS[0] = w2;
    }

    if (last) {
        __syncthreads();
        float wa = waS[0];
        if (wa != 0.0f) {
            const float* zb = z + (size_t)b * (SS * FF);
            float* ab = acc + (size_t)b * (SS * FF);
            for (int s = 0; s < SS; ++s)
                ab[s * FF + tid] += wa * (zb[s * FF + tid] + 0.1f * dltc);
        }
    }
}

// ---------------------------------------------------------------------------
extern "C" void kernel_launch(void* const* d_in, const int* in_sizes, int n_in,
                              void* d_out, int out_size, void* d_ws, size_t ws_size,
                              hipStream_t stream) {
    const float* z_real  = (const float*)d_in[0];
    const float* z_imag  = (const float*)d_in[1];
    const float* attn_wr = (const float*)d_in[2];
    const float* attn_wi = (const float*)d_in[3];
    const float* mem_wr  = (const float*)d_in[4];
    const float* mem_wi  = (const float*)d_in[5];
    const float* ctrl_w  = (const float*)d_in[6];
    const float* ctrl_b  = (const float*)d_in[7];
    const float* halt_w  = (const float*)d_in[8];
    const float* halt_b  = (const float*)d_in[9];
    const float* codebook  = (const float*)d_in[10];
    const float* adjacency = (const float*)d_in[11];

    float* ws = (float*)d_ws;
    float* z      = ws + Z_OFF;
    float* WT32   = ws + QKV_OFF;
    half_t* GTh   = (half_t*)(ws + QKV_OFF + 196608);
    half_t* GTl   = GTh + 65536;
    half_t* WvTh  = GTl + 65536;
    half_t* WvTl  = WvTh + 65536;
    float* Wv32m  = ws + WVM_OFF;
    float* mv     = ws + MV_OFF;
    float* sigma  = ws + SIG_OFF;
    float* zf1    = ws + ZF1_OFF;
    float* zf2    = ws + ZF2_OFF;
    float* readv  = ws + READ_OFF;
    float* probs  = ws + PROBS_OFF;
    float* delta  = ws + DELTA_OFF;
    float* halt   = ws + HALT_OFF;
    float* pval   = ws + PVAL_OFF;
    float* wact   = ws + WACT_OFF;
    float* magp   = ws + MAGP_OFF;
    float* cb2    = ws + CB2_OFF;
    float* acc    = (float*)d_out;

    k_buildwt32<<<768, 256, 0, stream>>>(attn_wr, attn_wi, WT32);
    k_buildG<<<256, 256, 0, stream>>>(WT32, GTh, GTl);
    k_splitWv<<<256, 256, 0, stream>>>(WT32, WvTh, WvTl);
    k_buildWv32m<<<256, 256, 0, stream>>>(mem_wr, mem_wi, Wv32m);
    k_cb2<<<1, 128, 0, stream>>>(codebook, cb2);
    k_init<<<32768, 256, 0, stream>>>(z_real, z_imag, z, mv, sigma, halt, acc,
                                      delta, wact);

    for (int t = 0; t < NDEPTH; ++t) {
        k_attn8<<<BB, 512, 0, stream>>>(z, GTh, GTl, WvTh, WvTl, delta, wact, acc, zf1);
        k_stack3<<<BB, 256, 0, stream>>>(zf1, ctrl_w, ctrl_b, sigma, mv, Wv32m,
                                         readv, zf2, halt_w, halt_b, pval, z, magp);
        k_vq2<<<BB, 256, 0, stream>>>(zf2, readv, probs, halt, pval, magp,
                                      codebook, cb2, adjacency, delta, wact,
                                      z, acc, t, (t == NDEPTH - 1) ? 1 : 0);
    }
}